// Round 3
// baseline (579.249 us; speedup 1.0000x reference)
//
#include <hip/hip_runtime.h>
#include <hip/hip_bf16.h>

#define TSEQ 2048
#define CDIM 2048
#define NH   16
#define NKV  4
#define HDIM 128
#define BATCH 2
#define MROWS (BATCH*TSEQ)   // 4096
#define KVC   (NKV*HDIM)     // 512

typedef short bf16x8 __attribute__((ext_vector_type(8)));
typedef float f32x4  __attribute__((ext_vector_type(4)));

__device__ inline f32x4 mfma16(bf16x8 a, bf16x8 b, f32x4 c) {
  return __builtin_amdgcn_mfma_f32_16x16x32_bf16(a, b, c, 0, 0, 0);
}

__device__ inline float bfbits2f(unsigned short u) {
  return __uint_as_float(((unsigned)u) << 16);
}

// ---- dtype canary: decide if inputs are bf16 (flag=1) or f32 (flag=0) ----
// Even-indexed bf16 decode of genuine bf16 N(0,1) data: ~100% in [1e-6,1e3].
// Even-indexed bf16 decode of f32 data (= f32 mantissa low bits): ~12%.
__global__ void canary(const void* __restrict__ x, int* __restrict__ flag) {
  __shared__ int cnt[256];
  int tid = threadIdx.x;
  const unsigned short* u = (const unsigned short*)x;
  int c = 0;
#pragma unroll
  for (int i = 0; i < 4; ++i) {
    float a = fabsf(bfbits2f(u[(tid*4 + i)*2]));
    if (a >= 1e-6f && a <= 1e3f) c++;
  }
  cnt[tid] = c;
  __syncthreads();
  for (int s = 128; s > 0; s >>= 1) {
    if (tid < s) cnt[tid] += cnt[tid + s];
    __syncthreads();
  }
  if (tid == 0) *flag = (cnt[0] > 512) ? 1 : 0;
}

// ---- canonize: produce a known-bf16 copy of an input tensor ----
__global__ __launch_bounds__(256) void canonize(
    const void* __restrict__ src, __hip_bfloat16* __restrict__ dst,
    int n, const int* __restrict__ flag) {
  int base = (blockIdx.x * 256 + threadIdx.x) * 8;
  if (base >= n) return;
  if (*flag) {
    *(bf16x8*)&dst[base] = *(const bf16x8*)((const __hip_bfloat16*)src + base);
  } else {
    const float* s = (const float*)src + base;
#pragma unroll
    for (int j = 0; j < 8; ++j) dst[base + j] = __float2bfloat16(s[j]);
  }
}

// C[m,n] = sum_k A[m,k] * B[n,k]  (A:[M][K], B:[N][K] bf16) -> C bf16
__global__ __launch_bounds__(256, 2) void gemm_bt(
    const __hip_bfloat16* __restrict__ A,
    const __hip_bfloat16* __restrict__ B,
    __hip_bfloat16* __restrict__ C,
    int M, int N, int K)
{
  __shared__ __align__(16) __hip_bfloat16 As[128*32];
  __shared__ __align__(16) __hip_bfloat16 Bs[128*32];
  const int tid  = threadIdx.x;
  const int wave = tid >> 6;
  const int lane = tid & 63;
  const int qd   = lane >> 4;
  const int ln   = lane & 15;
  const int m0   = blockIdx.y * 128;
  const int n0   = blockIdx.x * 128;
  const int wm   = (wave >> 1) * 64;
  const int wn   = (wave & 1) * 64;

  f32x4 acc[4][4] = {};

  for (int k0 = 0; k0 < K; k0 += 32) {
    bf16x8 a_st[2], b_st[2];
#pragma unroll
    for (int r = 0; r < 2; ++r) {
      int e   = (r*256 + tid) * 8;
      int row = e >> 5;
      int col = e & 31;
      a_st[r] = *(const bf16x8*)&A[(size_t)(m0+row)*K + k0 + col];
      b_st[r] = *(const bf16x8*)&B[(size_t)(n0+row)*K + k0 + col];
    }
    __syncthreads();
#pragma unroll
    for (int r = 0; r < 2; ++r) {
      int e = (r*256 + tid) * 8;
      *(bf16x8*)&As[e] = a_st[r];
      *(bf16x8*)&Bs[e] = b_st[r];
    }
    __syncthreads();
    bf16x8 af[4], bfr[4];
#pragma unroll
    for (int i = 0; i < 4; ++i)
      af[i] = *(const bf16x8*)&As[(wm + i*16 + ln)*32 + qd*8];
#pragma unroll
    for (int j = 0; j < 4; ++j)
      bfr[j] = *(const bf16x8*)&Bs[(wn + j*16 + ln)*32 + qd*8];
#pragma unroll
    for (int i = 0; i < 4; ++i)
#pragma unroll
      for (int j = 0; j < 4; ++j)
        acc[i][j] = mfma16(af[i], bfr[j], acc[i][j]);
  }
#pragma unroll
  for (int i = 0; i < 4; ++i)
#pragma unroll
    for (int j = 0; j < 4; ++j) {
      int row = m0 + wm + i*16 + qd*4;
      int col = n0 + wn + j*16 + ln;
#pragma unroll
      for (int r = 0; r < 4; ++r)
        C[(size_t)(row + r)*N + col] = __float2bfloat16(acc[i][j][r]);
    }
}

// Same GEMM, but epilogue writes bf16 or f32 to d_out per the canary flag.
__global__ __launch_bounds__(256, 2) void gemm_out(
    const __hip_bfloat16* __restrict__ A,
    const __hip_bfloat16* __restrict__ B,
    void* __restrict__ C,
    int M, int N, int K, const int* __restrict__ flag)
{
  __shared__ __align__(16) __hip_bfloat16 As[128*32];
  __shared__ __align__(16) __hip_bfloat16 Bs[128*32];
  const int tid  = threadIdx.x;
  const int wave = tid >> 6;
  const int lane = tid & 63;
  const int qd   = lane >> 4;
  const int ln   = lane & 15;
  const int m0   = blockIdx.y * 128;
  const int n0   = blockIdx.x * 128;
  const int wm   = (wave >> 1) * 64;
  const int wn   = (wave & 1) * 64;

  f32x4 acc[4][4] = {};

  for (int k0 = 0; k0 < K; k0 += 32) {
    bf16x8 a_st[2], b_st[2];
#pragma unroll
    for (int r = 0; r < 2; ++r) {
      int e   = (r*256 + tid) * 8;
      int row = e >> 5;
      int col = e & 31;
      a_st[r] = *(const bf16x8*)&A[(size_t)(m0+row)*K + k0 + col];
      b_st[r] = *(const bf16x8*)&B[(size_t)(n0+row)*K + k0 + col];
    }
    __syncthreads();
#pragma unroll
    for (int r = 0; r < 2; ++r) {
      int e = (r*256 + tid) * 8;
      *(bf16x8*)&As[e] = a_st[r];
      *(bf16x8*)&Bs[e] = b_st[r];
    }
    __syncthreads();
    bf16x8 af[4], bfr[4];
#pragma unroll
    for (int i = 0; i < 4; ++i)
      af[i] = *(const bf16x8*)&As[(wm + i*16 + ln)*32 + qd*8];
#pragma unroll
    for (int j = 0; j < 4; ++j)
      bfr[j] = *(const bf16x8*)&Bs[(wn + j*16 + ln)*32 + qd*8];
#pragma unroll
    for (int i = 0; i < 4; ++i)
#pragma unroll
      for (int j = 0; j < 4; ++j)
        acc[i][j] = mfma16(af[i], bfr[j], acc[i][j]);
  }
  const bool isbf = (*flag != 0);
#pragma unroll
  for (int i = 0; i < 4; ++i)
#pragma unroll
    for (int j = 0; j < 4; ++j) {
      int row = m0 + wm + i*16 + qd*4;
      int col = n0 + wn + j*16 + ln;
#pragma unroll
      for (int r = 0; r < 4; ++r) {
        if (isbf) ((__hip_bfloat16*)C)[(size_t)(row + r)*N + col] = __float2bfloat16(acc[i][j][r]);
        else      ((float*)C)[(size_t)(row + r)*N + col] = acc[i][j][r];
      }
    }
}

// RMSNorm + RoPE + (gain/sqrt(HD) for q), IN PLACE on bf16 q/k buffers.
// One wave per (row m, head). Lane i owns pair (2i, 2i+1).
__global__ __launch_bounds__(256) void prep_qk(
    __hip_bfloat16* __restrict__ qb,   // [4096][2048] in place
    __hip_bfloat16* __restrict__ kb,   // [4096][512]  in place
    const __hip_bfloat16* __restrict__ gain)  // [16]
{
  int wid  = blockIdx.x * 4 + (threadIdx.x >> 6);
  int lane = threadIdx.x & 63;
  bool isq = wid < MROWS*NH;
  int m, h;
  __hip_bfloat16* p;
  if (isq) { m = wid >> 4; h = wid & 15; p = qb + (size_t)m*CDIM + h*HDIM; }
  else     { int w2 = wid - MROWS*NH; m = w2 >> 2; h = w2 & 3; p = kb + (size_t)m*KVC + h*HDIM; }

  ushort2 raw = *(const ushort2*)((const unsigned short*)p + 2*lane);
  float e = bfbits2f(raw.x), o = bfbits2f(raw.y);
  float ss = e*e + o*o;
#pragma unroll
  for (int off = 32; off >= 1; off >>= 1) ss += __shfl_xor(ss, off);
  float rms = rsqrtf(ss * (1.0f/128.0f) + 1.1920928955078125e-07f);
  e *= rms; o *= rms;

  float theta = exp2f(-(float)(2*lane) * (1.0f/128.0f) * 13.287712379549449f);
  int t = m & (TSEQ-1);
  float fr = (float)t * theta;
  float c = cosf(fr), s = sinf(fr);
  float re = e*c - o*s;
  float ro = e*s + o*c;

  if (isq) {
    float g = bfbits2f(*(const unsigned short*)&gain[h]) * 0.08838834764831845f; // gain/sqrt(128)
    re *= g; ro *= g;
  }
  p[2*lane]   = __float2bfloat16(re);
  p[2*lane+1] = __float2bfloat16(ro);
}

// v_bf [4096][512] -> vt [B][NKV][HDIM][TSEQ]  (both bf16)
__global__ __launch_bounds__(256) void transpose_v(
    const __hip_bfloat16* __restrict__ v, __hip_bfloat16* __restrict__ vt)
{
  __shared__ __hip_bfloat16 tile[32][34];
  int tx = threadIdx.x & 31;
  int ty = threadIdx.x >> 5;  // 0..7
  int r0 = blockIdx.x * 32;   // (b*T+t) tile
  int c0 = blockIdx.y * 32;   // (hk*128+d) tile
#pragma unroll
  for (int i = 0; i < 4; ++i)
    tile[ty + i*8][tx] = v[(size_t)(r0 + ty + i*8)*KVC + c0 + tx];
  __syncthreads();
  int b = r0 >> 11;
  int t = r0 & (TSEQ-1);
  int hk = c0 >> 7;
  int d0 = c0 & (HDIM-1);
#pragma unroll
  for (int i = 0; i < 4; ++i) {
    int d = d0 + ty + i*8;
    vt[((size_t)((b*NKV + hk)*HDIM + d))*TSEQ + t + tx] = tile[tx][ty + i*8];
  }
}

// Flash attention, IN PLACE: reads Q-tile from qb, writes output over the
// same rows/head slice of qb. 1 wave per block, q-tile 32, k-tiles 32.
__global__ __launch_bounds__(64) void attn_kernel(
    __hip_bfloat16* __restrict__ qb,        // [B][T][NH*HD] (prep'd; becomes output)
    const __hip_bfloat16* __restrict__ kb,  // [B][T][NKV*HD] (prep'd)
    const __hip_bfloat16* __restrict__ vt)  // [B][NKV][HD][T]
{
  const int lane = threadIdx.x;
  const int qd = lane >> 4, ln = lane & 15;
  const int qt = blockIdx.x;
  const int h  = blockIdx.y;
  const int b  = blockIdx.z;
  const int hk = h >> 2;
  const int q0 = qt * 32;

  __hip_bfloat16* Q = qb + ((size_t)(b*TSEQ + q0))*CDIM + h*HDIM;   // row stride CDIM
  const __hip_bfloat16* K = kb + (size_t)(b*TSEQ)*KVC + hk*HDIM;    // row stride KVC
  const __hip_bfloat16* V = vt + ((size_t)(b*NKV + hk)*HDIM)*TSEQ;  // row stride TSEQ

  __shared__ __align__(16) __hip_bfloat16 Pb[32*32];

  bf16x8 qfr[2][4];
#pragma unroll
  for (int mt = 0; mt < 2; ++mt)
#pragma unroll
    for (int kc = 0; kc < 4; ++kc)
      qfr[mt][kc] = *(const bf16x8*)&Q[(size_t)(mt*16 + ln)*CDIM + kc*32 + qd*8];

  f32x4 o[2][8] = {};
  float mI[2][4], lI[2][4];
#pragma unroll
  for (int mt = 0; mt < 2; ++mt)
#pragma unroll
    for (int r = 0; r < 4; ++r) { mI[mt][r] = -1.0e30f; lI[mt][r] = 0.0f; }

  const int ktiles = qt + 1;
  for (int kt = 0; kt < ktiles; ++kt) {
    const int t0 = kt * 32;
    f32x4 s[2][2] = {};
#pragma unroll
    for (int nt = 0; nt < 2; ++nt) {
      bf16x8 kfr[4];
#pragma unroll
      for (int kc = 0; kc < 4; ++kc)
        kfr[kc] = *(const bf16x8*)&K[(size_t)(t0 + nt*16 + ln)*KVC + kc*32 + qd*8];
#pragma unroll
      for (int mt = 0; mt < 2; ++mt)
#pragma unroll
        for (int kc = 0; kc < 4; ++kc)
          s[mt][nt] = mfma16(qfr[mt][kc], kfr[kc], s[mt][nt]);
    }
    if (kt == qt) {
#pragma unroll
      for (int mt = 0; mt < 2; ++mt)
#pragma unroll
        for (int nt = 0; nt < 2; ++nt)
#pragma unroll
          for (int r = 0; r < 4; ++r) {
            int row = q0 + mt*16 + qd*4 + r;
            int col = t0 + nt*16 + ln;
            if (col > row) s[mt][nt][r] = -1.0e30f;
          }
    }
#pragma unroll
    for (int mt = 0; mt < 2; ++mt) {
#pragma unroll
      for (int r = 0; r < 4; ++r) {
        float v = fmaxf(s[mt][0][r], s[mt][1][r]);
        v = fmaxf(v, __shfl_xor(v, 1));
        v = fmaxf(v, __shfl_xor(v, 2));
        v = fmaxf(v, __shfl_xor(v, 4));
        v = fmaxf(v, __shfl_xor(v, 8));
        float mNew = fmaxf(mI[mt][r], v);
        float alpha = __expf(mI[mt][r] - mNew);
        float p0 = __expf(s[mt][0][r] - mNew);
        float p1 = __expf(s[mt][1][r] - mNew);
        s[mt][0][r] = p0; s[mt][1][r] = p1;
        float rs = p0 + p1;
        rs += __shfl_xor(rs, 1);
        rs += __shfl_xor(rs, 2);
        rs += __shfl_xor(rs, 4);
        rs += __shfl_xor(rs, 8);
        lI[mt][r] = lI[mt][r]*alpha + rs;
        mI[mt][r] = mNew;
#pragma unroll
        for (int dt = 0; dt < 8; ++dt) o[mt][dt][r] *= alpha;
      }
    }
    __syncthreads();
#pragma unroll
    for (int mt = 0; mt < 2; ++mt)
#pragma unroll
      for (int nt = 0; nt < 2; ++nt)
#pragma unroll
        for (int r = 0; r < 4; ++r)
          Pb[(mt*16 + qd*4 + r)*32 + nt*16 + ln] = __float2bfloat16(s[mt][nt][r]);
    __syncthreads();
    bf16x8 pa0 = *(const bf16x8*)&Pb[(ln)*32 + qd*8];
    bf16x8 pa1 = *(const bf16x8*)&Pb[(16 + ln)*32 + qd*8];
#pragma unroll
    for (int dt = 0; dt < 8; ++dt) {
      bf16x8 vf = *(const bf16x8*)&V[(size_t)(dt*16 + ln)*TSEQ + t0 + qd*8];
      o[0][dt] = mfma16(pa0, vf, o[0][dt]);
      o[1][dt] = mfma16(pa1, vf, o[1][dt]);
    }
  }

#pragma unroll
  for (int mt = 0; mt < 2; ++mt)
#pragma unroll
    for (int r = 0; r < 4; ++r) {
      float inv = 1.0f / lI[mt][r];
      int q = q0 + mt*16 + qd*4 + r;
      __hip_bfloat16* dst = qb + ((size_t)(b*TSEQ + q))*CDIM + h*HDIM;
#pragma unroll
      for (int dt = 0; dt < 8; ++dt)
        dst[dt*16 + ln] = __float2bfloat16(o[mt][dt][r] * inv);
    }
}

extern "C" void kernel_launch(void* const* d_in, const int* in_sizes, int n_in,
                              void* d_out, int out_size, void* d_ws, size_t ws_size,
                              hipStream_t stream) {
  char* ws = (char*)d_ws;
  size_t off = 0;
  auto alloc = [&](size_t bytes) { char* p = ws + off; off += (bytes + 255) & ~(size_t)255; return p; };

  int* flag = (int*)alloc(256);
  __hip_bfloat16* xb  = (__hip_bfloat16*)alloc((size_t)MROWS*CDIM*2);   // 16.8 MB
  __hip_bfloat16* wqb = (__hip_bfloat16*)alloc((size_t)CDIM*CDIM*2);    //  8.4 MB
  __hip_bfloat16* wkb = (__hip_bfloat16*)alloc((size_t)KVC*CDIM*2);     //  2.1 MB
  __hip_bfloat16* wvb = (__hip_bfloat16*)alloc((size_t)KVC*CDIM*2);     //  2.1 MB
  __hip_bfloat16* wob = (__hip_bfloat16*)alloc((size_t)CDIM*CDIM*2);    //  8.4 MB
  __hip_bfloat16* gb  = (__hip_bfloat16*)alloc(256);
  __hip_bfloat16* qb  = (__hip_bfloat16*)alloc((size_t)MROWS*CDIM*2);   // 16.8 MB
  __hip_bfloat16* kb  = (__hip_bfloat16*)alloc((size_t)MROWS*KVC*2);    //  4.2 MB
  __hip_bfloat16* vb  = (__hip_bfloat16*)alloc((size_t)MROWS*KVC*2);    //  4.2 MB
  __hip_bfloat16* vt  = (__hip_bfloat16*)alloc((size_t)MROWS*KVC*2);    //  4.2 MB
  // total ~67.2 MB

  // 0: dtype canary on x
  canary<<<1, 256, 0, stream>>>(d_in[0], flag);

  // 1: canonize all inputs to bf16
  canonize<<<(MROWS*CDIM)/(8*256), 256, 0, stream>>>(d_in[0], xb,  MROWS*CDIM, flag);
  canonize<<<(CDIM*CDIM)/(8*256),  256, 0, stream>>>(d_in[1], wqb, CDIM*CDIM,  flag);
  canonize<<<(KVC*CDIM)/(8*256),   256, 0, stream>>>(d_in[2], wkb, KVC*CDIM,   flag);
  canonize<<<(KVC*CDIM)/(8*256),   256, 0, stream>>>(d_in[3], wvb, KVC*CDIM,   flag);
  canonize<<<(CDIM*CDIM)/(8*256),  256, 0, stream>>>(d_in[4], wob, CDIM*CDIM,  flag);
  canonize<<<1, 256, 0, stream>>>(d_in[5], gb, NH, flag);

  // 2: projections
  gemm_bt<<<dim3(CDIM/128, MROWS/128), 256, 0, stream>>>(xb, wqb, qb, MROWS, CDIM, CDIM);
  gemm_bt<<<dim3(KVC/128,  MROWS/128), 256, 0, stream>>>(xb, wkb, kb, MROWS, KVC, CDIM);
  gemm_bt<<<dim3(KVC/128,  MROWS/128), 256, 0, stream>>>(xb, wvb, vb, MROWS, KVC, CDIM);

  // 3: RMS + RoPE + gain, in place
  int nwaves = MROWS*NH + MROWS*NKV;  // 81920
  prep_qk<<<nwaves/4, 256, 0, stream>>>(qb, kb, gb);

  // 4: V transpose
  transpose_v<<<dim3(MROWS/32, KVC/32), 256, 0, stream>>>(vb, vt);

  // 5: attention (in place over qb)
  attn_kernel<<<dim3(TSEQ/32, NH, BATCH), 64, 0, stream>>>(qb, kb, vt);

  // 6: output projection -> d_out (dtype per flag)
  gemm_out<<<dim3(CDIM/128, MROWS/128), 256, 0, stream>>>(qb, wob, d_out, MROWS, CDIM, CDIM, flag);
}

// Round 4
// 501.525 us; speedup vs baseline: 1.1550x; 1.1550x over previous
//
#include <hip/hip_runtime.h>
#include <hip/hip_bf16.h>

#define TSEQ 2048
#define CDIM 2048
#define NH   16
#define NKV  4
#define HDIM 128
#define BATCH 2
#define MROWS (BATCH*TSEQ)   // 4096
#define KVC   (NKV*HDIM)     // 512

typedef short bf16x8 __attribute__((ext_vector_type(8)));
typedef float f32x4  __attribute__((ext_vector_type(4)));

typedef const __attribute__((address_space(1))) void* gptr_t;
typedef __attribute__((address_space(3))) void* sptr_t;

__device__ inline void async16(const __hip_bfloat16* g, __hip_bfloat16* l) {
  __builtin_amdgcn_global_load_lds((gptr_t)g, (sptr_t)l, 16, 0, 0);
}

__device__ inline f32x4 mfma16(bf16x8 a, bf16x8 b, f32x4 c) {
  return __builtin_amdgcn_mfma_f32_16x16x32_bf16(a, b, c, 0, 0, 0);
}

__device__ inline float bfbits2f(unsigned short u) {
  return __uint_as_float(((unsigned)u) << 16);
}

// LDS XOR-swizzles: break the row-stride bank aliasing for 16B fragment reads.
__device__ inline int swz128(int row, int col) {  // rows of 128 bf16, 16 chunks
  return row*128 + (((col >> 3) ^ (row & 15)) << 3) + (col & 7);
}
__device__ inline int swz64(int row, int col) {   // rows of 64 bf16, 8 chunks
  return row*64 + ((((col >> 3) ^ row) & 7) << 3) + (col & 7);
}

// ---- dtype canary: inputs bf16 (flag=1) or f32 (flag=0) ----
__global__ void canary(const void* __restrict__ x, int* __restrict__ flag) {
  __shared__ int cnt[256];
  int tid = threadIdx.x;
  const unsigned short* u = (const unsigned short*)x;
  int c = 0;
#pragma unroll
  for (int i = 0; i < 4; ++i) {
    float a = fabsf(bfbits2f(u[(tid*4 + i)*2]));
    if (a >= 1e-6f && a <= 1e3f) c++;
  }
  cnt[tid] = c;
  __syncthreads();
  for (int s = 128; s > 0; s >>= 1) {
    if (tid < s) cnt[tid] += cnt[tid + s];
    __syncthreads();
  }
  if (tid == 0) *flag = (cnt[0] > 512) ? 1 : 0;
}

// ---- canonize: known-bf16 copy of an input tensor ----
__global__ __launch_bounds__(256) void canonize(
    const void* __restrict__ src, __hip_bfloat16* __restrict__ dst,
    int n, const int* __restrict__ flag) {
  int base = (blockIdx.x * 256 + threadIdx.x) * 8;
  if (base >= n) return;
  if (*flag) {
    *(bf16x8*)&dst[base] = *(const bf16x8*)((const __hip_bfloat16*)src + base);
  } else {
    const float* s = (const float*)src + base;
#pragma unroll
    for (int j = 0; j < 8; ++j) dst[base + j] = __float2bfloat16(s[j]);
  }
}

// C[m,n] = sum_k A[m,k]*B[n,k]; m97-style async staging.
__global__ __launch_bounds__(256, 2) void gemm_bt(
    const __hip_bfloat16* __restrict__ A,
    const __hip_bfloat16* __restrict__ B,
    __hip_bfloat16* __restrict__ C,
    int M, int N, int K)
{
  __shared__ __align__(16) __hip_bfloat16 As[128*32];
  __shared__ __align__(16) __hip_bfloat16 Bs[128*32];
  const int tid  = threadIdx.x;
  const int wave = tid >> 6;
  const int lane = tid & 63;
  const int qd   = lane >> 4;
  const int ln   = lane & 15;
  const int m0   = blockIdx.y * 128;
  const int n0   = blockIdx.x * 128;
  const int wm   = (wave >> 1) * 64;
  const int wn   = (wave & 1) * 64;

  f32x4 acc[4][4] = {};

  for (int k0 = 0; k0 < K; k0 += 32) {
    __syncthreads();
#pragma unroll
    for (int r = 0; r < 2; ++r) {
      int e   = (r*256 + tid) * 8;
      int row = e >> 5;
      int col = e & 31;
      async16(&A[(size_t)(m0+row)*K + k0 + col], &As[(size_t)(r*256 + wave*64)*8]);
      async16(&B[(size_t)(n0+row)*K + k0 + col], &Bs[(size_t)(r*256 + wave*64)*8]);
    }
    __syncthreads();
    bf16x8 af[4], bfr[4];
#pragma unroll
    for (int i = 0; i < 4; ++i)
      af[i] = *(const bf16x8*)&As[(wm + i*16 + ln)*32 + qd*8];
#pragma unroll
    for (int j = 0; j < 4; ++j)
      bfr[j] = *(const bf16x8*)&Bs[(wn + j*16 + ln)*32 + qd*8];
#pragma unroll
    for (int i = 0; i < 4; ++i)
#pragma unroll
      for (int j = 0; j < 4; ++j)
        acc[i][j] = mfma16(af[i], bfr[j], acc[i][j]);
  }
#pragma unroll
  for (int i = 0; i < 4; ++i)
#pragma unroll
    for (int j = 0; j < 4; ++j) {
      int row = m0 + wm + i*16 + qd*4;
      int col = n0 + wn + j*16 + ln;
#pragma unroll
      for (int r = 0; r < 4; ++r)
        C[(size_t)(row + r)*N + col] = __float2bfloat16(acc[i][j][r]);
    }
}

// Same GEMM; epilogue dtype per flag (d_out matches input dtype).
__global__ __launch_bounds__(256, 2) void gemm_out(
    const __hip_bfloat16* __restrict__ A,
    const __hip_bfloat16* __restrict__ B,
    void* __restrict__ C,
    int M, int N, int K, const int* __restrict__ flag)
{
  __shared__ __align__(16) __hip_bfloat16 As[128*32];
  __shared__ __align__(16) __hip_bfloat16 Bs[128*32];
  const int tid  = threadIdx.x;
  const int wave = tid >> 6;
  const int lane = tid & 63;
  const int qd   = lane >> 4;
  const int ln   = lane & 15;
  const int m0   = blockIdx.y * 128;
  const int n0   = blockIdx.x * 128;
  const int wm   = (wave >> 1) * 64;
  const int wn   = (wave & 1) * 64;

  f32x4 acc[4][4] = {};

  for (int k0 = 0; k0 < K; k0 += 32) {
    __syncthreads();
#pragma unroll
    for (int r = 0; r < 2; ++r) {
      int e   = (r*256 + tid) * 8;
      int row = e >> 5;
      int col = e & 31;
      async16(&A[(size_t)(m0+row)*K + k0 + col], &As[(size_t)(r*256 + wave*64)*8]);
      async16(&B[(size_t)(n0+row)*K + k0 + col], &Bs[(size_t)(r*256 + wave*64)*8]);
    }
    __syncthreads();
    bf16x8 af[4], bfr[4];
#pragma unroll
    for (int i = 0; i < 4; ++i)
      af[i] = *(const bf16x8*)&As[(wm + i*16 + ln)*32 + qd*8];
#pragma unroll
    for (int j = 0; j < 4; ++j)
      bfr[j] = *(const bf16x8*)&Bs[(wn + j*16 + ln)*32 + qd*8];
#pragma unroll
    for (int i = 0; i < 4; ++i)
#pragma unroll
      for (int j = 0; j < 4; ++j)
        acc[i][j] = mfma16(af[i], bfr[j], acc[i][j]);
  }
  const bool isbf = (*flag != 0);
#pragma unroll
  for (int i = 0; i < 4; ++i)
#pragma unroll
    for (int j = 0; j < 4; ++j) {
      int row = m0 + wm + i*16 + qd*4;
      int col = n0 + wn + j*16 + ln;
#pragma unroll
      for (int r = 0; r < 4; ++r) {
        if (isbf) ((__hip_bfloat16*)C)[(size_t)(row + r)*N + col] = __float2bfloat16(acc[i][j][r]);
        else      ((float*)C)[(size_t)(row + r)*N + col] = acc[i][j][r];
      }
    }
}

// RMSNorm + RoPE + (gain/sqrt(HD) for q), in place on bf16 buffers.
__global__ __launch_bounds__(256) void prep_qk(
    __hip_bfloat16* __restrict__ qb,   // [4096][2048]
    __hip_bfloat16* __restrict__ kb,   // [4096][512]
    const __hip_bfloat16* __restrict__ gain)
{
  int wid  = blockIdx.x * 4 + (threadIdx.x >> 6);
  int lane = threadIdx.x & 63;
  bool isq = wid < MROWS*NH;
  int m, h;
  __hip_bfloat16* p;
  if (isq) { m = wid >> 4; h = wid & 15; p = qb + (size_t)m*CDIM + h*HDIM; }
  else     { int w2 = wid - MROWS*NH; m = w2 >> 2; h = w2 & 3; p = kb + (size_t)m*KVC + h*HDIM; }

  ushort2 raw = *(const ushort2*)((const unsigned short*)p + 2*lane);
  float e = bfbits2f(raw.x), o = bfbits2f(raw.y);
  float ss = e*e + o*o;
#pragma unroll
  for (int off = 32; off >= 1; off >>= 1) ss += __shfl_xor(ss, off);
  float rms = rsqrtf(ss * (1.0f/128.0f) + 1.1920928955078125e-07f);
  e *= rms; o *= rms;

  float theta = exp2f(-(float)(2*lane) * (1.0f/128.0f) * 13.287712379549449f);
  int t = m & (TSEQ-1);
  float fr = (float)t * theta;
  float c = cosf(fr), s = sinf(fr);
  float re = e*c - o*s;
  float ro = e*s + o*c;

  if (isq) {
    float g = bfbits2f(*(const unsigned short*)&gain[h]) * 0.08838834764831845f;
    re *= g; ro *= g;
  }
  p[2*lane]   = __float2bfloat16(re);
  p[2*lane+1] = __float2bfloat16(ro);
}

// v_bf [4096][512] -> vt [B][NKV][HDIM][TSEQ]
__global__ __launch_bounds__(256) void transpose_v(
    const __hip_bfloat16* __restrict__ v, __hip_bfloat16* __restrict__ vt)
{
  __shared__ __hip_bfloat16 tile[32][34];
  int tx = threadIdx.x & 31;
  int ty = threadIdx.x >> 5;
  int r0 = blockIdx.x * 32;
  int c0 = blockIdx.y * 32;
#pragma unroll
  for (int i = 0; i < 4; ++i)
    tile[ty + i*8][tx] = v[(size_t)(r0 + ty + i*8)*KVC + c0 + tx];
  __syncthreads();
  int b = r0 >> 11;
  int t = r0 & (TSEQ-1);
  int hk = c0 >> 7;
  int d0 = c0 & (HDIM-1);
#pragma unroll
  for (int i = 0; i < 4; ++i) {
    int d = d0 + ty + i*8;
    vt[((size_t)((b*NKV + hk)*HDIM + d))*TSEQ + t + tx] = tile[tx][ty + i*8];
  }
}

// Flash attention v2: 256-thr blocks (4 waves), q-block 64 (16 rows/wave),
// K-tile 64 staged in swizzled LDS shared by the 4 waves. In place over qb.
__global__ __launch_bounds__(256, 4) void attn_kernel(
    __hip_bfloat16* __restrict__ qb,        // [B][T][NH*HD] -> overwritten with attn out
    const __hip_bfloat16* __restrict__ kb,  // [B][T][NKV*HD]
    const __hip_bfloat16* __restrict__ vt)  // [B][NKV][HD][T]
{
  const int tid  = threadIdx.x;
  const int wave = tid >> 6;
  const int lane = tid & 63;
  const int qd = lane >> 4, ln = lane & 15;
  const int qt = (gridDim.x - 1) - blockIdx.x;   // heavy (high-qt) blocks first
  const int h  = blockIdx.y;
  const int b  = blockIdx.z;
  const int hk = h >> 2;
  const int q0 = qt * 64;
  const int qw = q0 + wave * 16;

  __hip_bfloat16* Qp = qb + (size_t)(b*TSEQ)*CDIM + h*HDIM;
  const __hip_bfloat16* K = kb + (size_t)(b*TSEQ)*KVC + hk*HDIM;
  const __hip_bfloat16* V = vt + ((size_t)(b*NKV + hk)*HDIM)*TSEQ;

  __shared__ __align__(16) __hip_bfloat16 Ks[64*128];    // [t][d], swizzled
  __shared__ __align__(16) __hip_bfloat16 Vs[128*64];    // [d][t], swizzled
  __shared__ __align__(16) __hip_bfloat16 Pb[4*16*64];   // per-wave P, swizzled

  // Q fragments (A-layout): lane m=ln, k = kc*32 + qd*8
  bf16x8 qfr[4];
#pragma unroll
  for (int kc = 0; kc < 4; ++kc)
    qfr[kc] = *(const bf16x8*)&Qp[(size_t)(qw + ln)*CDIM + kc*32 + qd*8];

  f32x4 o[8] = {};
  float mI[4], lI[4];
#pragma unroll
  for (int r = 0; r < 4; ++r) { mI[r] = -1.0e30f; lI[r] = 0.0f; }

  const int ktiles = qt + 1;
  for (int kt = 0; kt < ktiles; ++kt) {
    const int t0 = kt * 64;
    __syncthreads();   // prior iteration's Ks/Vs reads complete
    // stage K tile [64][128]
#pragma unroll
    for (int i = 0; i < 4; ++i) {
      int e = (i*256 + tid) * 8;
      int row = e >> 7, col = e & 127;
      *(bf16x8*)&Ks[swz128(row, col)] = *(const bf16x8*)&K[(size_t)(t0 + row)*KVC + col];
    }
    // stage V tile [128][64]
#pragma unroll
    for (int i = 0; i < 4; ++i) {
      int e = (i*256 + tid) * 8;
      int row = e >> 6, col = e & 63;
      *(bf16x8*)&Vs[swz64(row, col)] = *(const bf16x8*)&V[(size_t)row*TSEQ + t0 + col];
    }
    __syncthreads();

    // S = Q K^T : 16 rows x 64 cols per wave
    f32x4 s[4] = {};
#pragma unroll
    for (int nt = 0; nt < 4; ++nt) {
#pragma unroll
      for (int kc = 0; kc < 4; ++kc) {
        bf16x8 kfr = *(const bf16x8*)&Ks[swz128(nt*16 + ln, kc*32 + qd*8)];
        s[nt] = mfma16(qfr[kc], kfr, s[nt]);
      }
    }
    if (kt == qt) {  // diagonal: causal mask
#pragma unroll
      for (int nt = 0; nt < 4; ++nt)
#pragma unroll
        for (int r = 0; r < 4; ++r) {
          int row = qw + qd*4 + r;
          int col = t0 + nt*16 + ln;
          if (col > row) s[nt][r] = -1.0e30f;
        }
    }
    // online softmax (row = 16-lane group of this quad)
#pragma unroll
    for (int r = 0; r < 4; ++r) {
      float v = fmaxf(fmaxf(s[0][r], s[1][r]), fmaxf(s[2][r], s[3][r]));
      v = fmaxf(v, __shfl_xor(v, 1));
      v = fmaxf(v, __shfl_xor(v, 2));
      v = fmaxf(v, __shfl_xor(v, 4));
      v = fmaxf(v, __shfl_xor(v, 8));
      float mNew = fmaxf(mI[r], v);
      float alpha = __expf(mI[r] - mNew);
      float p0 = __expf(s[0][r] - mNew);
      float p1 = __expf(s[1][r] - mNew);
      float p2 = __expf(s[2][r] - mNew);
      float p3 = __expf(s[3][r] - mNew);
      s[0][r] = p0; s[1][r] = p1; s[2][r] = p2; s[3][r] = p3;
      float rs = (p0 + p1) + (p2 + p3);
      rs += __shfl_xor(rs, 1);
      rs += __shfl_xor(rs, 2);
      rs += __shfl_xor(rs, 4);
      rs += __shfl_xor(rs, 8);
      lI[r] = lI[r]*alpha + rs;
      mI[r] = mNew;
#pragma unroll
      for (int dt = 0; dt < 8; ++dt) o[dt][r] *= alpha;
    }
    // P (C-layout) -> wave-private LDS -> A-layout (no barrier needed)
    __hip_bfloat16* Pw = &Pb[wave*1024];
#pragma unroll
    for (int nt = 0; nt < 4; ++nt)
#pragma unroll
      for (int r = 0; r < 4; ++r)
        Pw[swz64(qd*4 + r, nt*16 + ln)] = __float2bfloat16(s[nt][r]);
    bf16x8 pa[2];
#pragma unroll
    for (int kc = 0; kc < 2; ++kc)
      pa[kc] = *(const bf16x8*)&Pw[swz64(ln, kc*32 + qd*8)];
    // O += P V : B-frag n=d (dt*16+ln), k=t
#pragma unroll
    for (int dt = 0; dt < 8; ++dt) {
#pragma unroll
      for (int kc = 0; kc < 2; ++kc) {
        bf16x8 vf = *(const bf16x8*)&Vs[swz64(dt*16 + ln, kc*32 + qd*8)];
        o[dt] = mfma16(pa[kc], vf, o[dt]);
      }
    }
  }

  // epilogue (in place over this block's own q rows / head slice)
#pragma unroll
  for (int r = 0; r < 4; ++r) {
    float inv = 1.0f / lI[r];
    int q = qw + qd*4 + r;
    __hip_bfloat16* dst = qb + ((size_t)(b*TSEQ + q))*CDIM + h*HDIM;
#pragma unroll
    for (int dt = 0; dt < 8; ++dt)
      dst[dt*16 + ln] = __float2bfloat16(o[dt][r] * inv);
  }
}

extern "C" void kernel_launch(void* const* d_in, const int* in_sizes, int n_in,
                              void* d_out, int out_size, void* d_ws, size_t ws_size,
                              hipStream_t stream) {
  char* ws = (char*)d_ws;
  size_t off = 0;
  auto alloc = [&](size_t bytes) { char* p = ws + off; off += (bytes + 255) & ~(size_t)255; return p; };

  int* flag = (int*)alloc(256);
  __hip_bfloat16* xb  = (__hip_bfloat16*)alloc((size_t)MROWS*CDIM*2);
  __hip_bfloat16* wqb = (__hip_bfloat16*)alloc((size_t)CDIM*CDIM*2);
  __hip_bfloat16* wkb = (__hip_bfloat16*)alloc((size_t)KVC*CDIM*2);
  __hip_bfloat16* wvb = (__hip_bfloat16*)alloc((size_t)KVC*CDIM*2);
  __hip_bfloat16* wob = (__hip_bfloat16*)alloc((size_t)CDIM*CDIM*2);
  __hip_bfloat16* gb  = (__hip_bfloat16*)alloc(256);
  __hip_bfloat16* qb  = (__hip_bfloat16*)alloc((size_t)MROWS*CDIM*2);
  __hip_bfloat16* kb  = (__hip_bfloat16*)alloc((size_t)MROWS*KVC*2);
  __hip_bfloat16* vb  = (__hip_bfloat16*)alloc((size_t)MROWS*KVC*2);
  __hip_bfloat16* vt  = (__hip_bfloat16*)alloc((size_t)MROWS*KVC*2);

  canary<<<1, 256, 0, stream>>>(d_in[0], flag);

  canonize<<<(MROWS*CDIM)/(8*256), 256, 0, stream>>>(d_in[0], xb,  MROWS*CDIM, flag);
  canonize<<<(CDIM*CDIM)/(8*256),  256, 0, stream>>>(d_in[1], wqb, CDIM*CDIM,  flag);
  canonize<<<(KVC*CDIM)/(8*256),   256, 0, stream>>>(d_in[2], wkb, KVC*CDIM,   flag);
  canonize<<<(KVC*CDIM)/(8*256),   256, 0, stream>>>(d_in[3], wvb, KVC*CDIM,   flag);
  canonize<<<(CDIM*CDIM)/(8*256),  256, 0, stream>>>(d_in[4], wob, CDIM*CDIM,  flag);
  canonize<<<1, 256, 0, stream>>>(d_in[5], gb, NH, flag);

  gemm_bt<<<dim3(CDIM/128, MROWS/128), 256, 0, stream>>>(xb, wqb, qb, MROWS, CDIM, CDIM);
  gemm_bt<<<dim3(KVC/128,  MROWS/128), 256, 0, stream>>>(xb, wkb, kb, MROWS, KVC, CDIM);
  gemm_bt<<<dim3(KVC/128,  MROWS/128), 256, 0, stream>>>(xb, wvb, vb, MROWS, KVC, CDIM);

  int nwaves = MROWS*NH + MROWS*NKV;
  prep_qk<<<nwaves/4, 256, 0, stream>>>(qb, kb, gb);

  transpose_v<<<dim3(MROWS/32, KVC/32), 256, 0, stream>>>(vb, vt);

  attn_kernel<<<dim3(TSEQ/64, NH, BATCH), 256, 0, stream>>>(qb, kb, vt);

  gemm_out<<<dim3(CDIM/128, MROWS/128), 256, 0, stream>>>(qb, wob, d_out, MROWS, CDIM, CDIM, flag);
}

// Round 6
// 456.535 us; speedup vs baseline: 1.2688x; 1.0985x over previous
//
#include <hip/hip_runtime.h>
#include <hip/hip_bf16.h>

#define TSEQ 2048
#define CDIM 2048
#define NH   16
#define NKV  4
#define HDIM 128
#define BATCH 2
#define MROWS (BATCH*TSEQ)   // 4096
#define KVC   (NKV*HDIM)     // 512

typedef short bf16x8 __attribute__((ext_vector_type(8)));
typedef float f32x4  __attribute__((ext_vector_type(4)));

typedef const __attribute__((address_space(1))) void* gptr_t;
typedef __attribute__((address_space(3))) void* sptr_t;

__device__ inline void async16(const __hip_bfloat16* g, __hip_bfloat16* l) {
  __builtin_amdgcn_global_load_lds((gptr_t)g, (sptr_t)l, 16, 0, 0);
}

__device__ inline f32x4 mfma16(bf16x8 a, bf16x8 b, f32x4 c) {
  return __builtin_amdgcn_mfma_f32_16x16x32_bf16(a, b, c, 0, 0, 0);
}

__device__ inline float bfbits2f(unsigned short u) {
  return __uint_as_float(((unsigned)u) << 16);
}

// LDS XOR-swizzles: break row-stride bank aliasing for 16B fragment access.
__device__ inline int swz128(int row, int col) {  // rows of 128 bf16
  return row*128 + (((col >> 3) ^ (row & 15)) << 3) + (col & 7);
}
__device__ inline int swz64(int row, int col) {   // rows of 64 bf16
  return row*64 + ((((col >> 3) ^ row) & 7) << 3) + (col & 7);
}

// ---- dtype canary: inputs bf16 (flag=1) or f32 (flag=0) ----
__global__ void canary(const void* __restrict__ x, int* __restrict__ flag) {
  __shared__ int cnt[256];
  int tid = threadIdx.x;
  const unsigned short* u = (const unsigned short*)x;
  int c = 0;
#pragma unroll
  for (int i = 0; i < 4; ++i) {
    float a = fabsf(bfbits2f(u[(tid*4 + i)*2]));
    if (a >= 1e-6f && a <= 1e3f) c++;
  }
  cnt[tid] = c;
  __syncthreads();
  for (int s = 128; s > 0; s >>= 1) {
    if (tid < s) cnt[tid] += cnt[tid + s];
    __syncthreads();
  }
  if (tid == 0) *flag = (cnt[0] > 512) ? 1 : 0;
}

// ---- canonize: known-bf16 copy of an input tensor ----
__global__ __launch_bounds__(256) void canonize(
    const void* __restrict__ src, __hip_bfloat16* __restrict__ dst,
    int n, const int* __restrict__ flag) {
  int base = (blockIdx.x * 256 + threadIdx.x) * 8;
  if (base >= n) return;
  if (*flag) {
    *(bf16x8*)&dst[base] = *(const bf16x8*)((const __hip_bfloat16*)src + base);
  } else {
    const float* s = (const float*)src + base;
#pragma unroll
    for (int j = 0; j < 8; ++j) dst[base + j] = __float2bfloat16(s[j]);
  }
}

// C[m,n] = sum_k A[m,k]*B[n,k]; m97-style async staging.
__global__ __launch_bounds__(256, 2) void gemm_bt(
    const __hip_bfloat16* __restrict__ A,
    const __hip_bfloat16* __restrict__ B,
    __hip_bfloat16* __restrict__ C,
    int M, int N, int K)
{
  __shared__ __align__(16) __hip_bfloat16 As[128*32];
  __shared__ __align__(16) __hip_bfloat16 Bs[128*32];
  const int tid  = threadIdx.x;
  const int wave = tid >> 6;
  const int lane = tid & 63;
  const int qd   = lane >> 4;
  const int ln   = lane & 15;
  const int m0   = blockIdx.y * 128;
  const int n0   = blockIdx.x * 128;
  const int wm   = (wave >> 1) * 64;
  const int wn   = (wave & 1) * 64;

  f32x4 acc[4][4] = {};

  for (int k0 = 0; k0 < K; k0 += 32) {
    __syncthreads();
#pragma unroll
    for (int r = 0; r < 2; ++r) {
      int e   = (r*256 + tid) * 8;
      int row = e >> 5;
      int col = e & 31;
      async16(&A[(size_t)(m0+row)*K + k0 + col], &As[(size_t)(r*256 + wave*64)*8]);
      async16(&B[(size_t)(n0+row)*K + k0 + col], &Bs[(size_t)(r*256 + wave*64)*8]);
    }
    __syncthreads();
    bf16x8 af[4], bfr[4];
#pragma unroll
    for (int i = 0; i < 4; ++i)
      af[i] = *(const bf16x8*)&As[(wm + i*16 + ln)*32 + qd*8];
#pragma unroll
    for (int j = 0; j < 4; ++j)
      bfr[j] = *(const bf16x8*)&Bs[(wn + j*16 + ln)*32 + qd*8];
#pragma unroll
    for (int i = 0; i < 4; ++i)
#pragma unroll
      for (int j = 0; j < 4; ++j)
        acc[i][j] = mfma16(af[i], bfr[j], acc[i][j]);
  }
#pragma unroll
  for (int i = 0; i < 4; ++i)
#pragma unroll
    for (int j = 0; j < 4; ++j) {
      int row = m0 + wm + i*16 + qd*4;
      int col = n0 + wn + j*16 + ln;
#pragma unroll
      for (int r = 0; r < 4; ++r)
        C[(size_t)(row + r)*N + col] = __float2bfloat16(acc[i][j][r]);
    }
}

// Same GEMM; epilogue dtype per flag (d_out matches input dtype).
__global__ __launch_bounds__(256, 2) void gemm_out(
    const __hip_bfloat16* __restrict__ A,
    const __hip_bfloat16* __restrict__ B,
    void* __restrict__ C,
    int M, int N, int K, const int* __restrict__ flag)
{
  __shared__ __align__(16) __hip_bfloat16 As[128*32];
  __shared__ __align__(16) __hip_bfloat16 Bs[128*32];
  const int tid  = threadIdx.x;
  const int wave = tid >> 6;
  const int lane = tid & 63;
  const int qd   = lane >> 4;
  const int ln   = lane & 15;
  const int m0   = blockIdx.y * 128;
  const int n0   = blockIdx.x * 128;
  const int wm   = (wave >> 1) * 64;
  const int wn   = (wave & 1) * 64;

  f32x4 acc[4][4] = {};

  for (int k0 = 0; k0 < K; k0 += 32) {
    __syncthreads();
#pragma unroll
    for (int r = 0; r < 2; ++r) {
      int e   = (r*256 + tid) * 8;
      int row = e >> 5;
      int col = e & 31;
      async16(&A[(size_t)(m0+row)*K + k0 + col], &As[(size_t)(r*256 + wave*64)*8]);
      async16(&B[(size_t)(n0+row)*K + k0 + col], &Bs[(size_t)(r*256 + wave*64)*8]);
    }
    __syncthreads();
    bf16x8 af[4], bfr[4];
#pragma unroll
    for (int i = 0; i < 4; ++i)
      af[i] = *(const bf16x8*)&As[(wm + i*16 + ln)*32 + qd*8];
#pragma unroll
    for (int j = 0; j < 4; ++j)
      bfr[j] = *(const bf16x8*)&Bs[(wn + j*16 + ln)*32 + qd*8];
#pragma unroll
    for (int i = 0; i < 4; ++i)
#pragma unroll
      for (int j = 0; j < 4; ++j)
        acc[i][j] = mfma16(af[i], bfr[j], acc[i][j]);
  }
  const bool isbf = (*flag != 0);
#pragma unroll
  for (int i = 0; i < 4; ++i)
#pragma unroll
    for (int j = 0; j < 4; ++j) {
      int row = m0 + wm + i*16 + qd*4;
      int col = n0 + wn + j*16 + ln;
#pragma unroll
      for (int r = 0; r < 4; ++r) {
        if (isbf) ((__hip_bfloat16*)C)[(size_t)(row + r)*N + col] = __float2bfloat16(acc[i][j][r]);
        else      ((float*)C)[(size_t)(row + r)*N + col] = acc[i][j][r];
      }
    }
}

// RMSNorm + RoPE + (gain/sqrt(HD) for q), in place on bf16 buffers.
__global__ __launch_bounds__(256) void prep_qk(
    __hip_bfloat16* __restrict__ qb,   // [4096][2048]
    __hip_bfloat16* __restrict__ kb,   // [4096][512]
    const __hip_bfloat16* __restrict__ gain)
{
  int wid  = blockIdx.x * 4 + (threadIdx.x >> 6);
  int lane = threadIdx.x & 63;
  bool isq = wid < MROWS*NH;
  int m, h;
  __hip_bfloat16* p;
  if (isq) { m = wid >> 4; h = wid & 15; p = qb + (size_t)m*CDIM + h*HDIM; }
  else     { int w2 = wid - MROWS*NH; m = w2 >> 2; h = w2 & 3; p = kb + (size_t)m*KVC + h*HDIM; }

  ushort2 raw = *(const ushort2*)((const unsigned short*)p + 2*lane);
  float e = bfbits2f(raw.x), o = bfbits2f(raw.y);
  float ss = e*e + o*o;
#pragma unroll
  for (int off = 32; off >= 1; off >>= 1) ss += __shfl_xor(ss, off);
  float rms = rsqrtf(ss * (1.0f/128.0f) + 1.1920928955078125e-07f);
  e *= rms; o *= rms;

  float theta = exp2f(-(float)(2*lane) * (1.0f/128.0f) * 13.287712379549449f);
  int t = m & (TSEQ-1);
  float fr = (float)t * theta;
  float c = cosf(fr), s = sinf(fr);
  float re = e*c - o*s;
  float ro = e*s + o*c;

  if (isq) {
    float g = bfbits2f(*(const unsigned short*)&gain[h]) * 0.08838834764831845f;
    re *= g; ro *= g;
  }
  p[2*lane]   = __float2bfloat16(re);
  p[2*lane+1] = __float2bfloat16(ro);
}

// v_bf [4096][512] -> vt [B][NKV][HDIM][TSEQ]
__global__ __launch_bounds__(256) void transpose_v(
    const __hip_bfloat16* __restrict__ v, __hip_bfloat16* __restrict__ vt)
{
  __shared__ __hip_bfloat16 tile[32][34];
  int tx = threadIdx.x & 31;
  int ty = threadIdx.x >> 5;
  int r0 = blockIdx.x * 32;
  int c0 = blockIdx.y * 32;
#pragma unroll
  for (int i = 0; i < 4; ++i)
    tile[ty + i*8][tx] = v[(size_t)(r0 + ty + i*8)*KVC + c0 + tx];
  __syncthreads();
  int b = r0 >> 11;
  int t = r0 & (TSEQ-1);
  int hk = c0 >> 7;
  int d0 = c0 & (HDIM-1);
#pragma unroll
  for (int i = 0; i < 4; ++i) {
    int d = d0 + ty + i*8;
    vt[((size_t)((b*NKV + hk)*HDIM + d))*TSEQ + t + tx] = tile[tx][ty + i*8];
  }
}

// Flash attention v4 = round-4 validated staging + fixed-offset softmax +
// barrier-hardened coalesced LDS epilogue. 256 thr (4 waves), q-block 64
// (16 rows/wave), K-tile 64 in swizzled LDS. In place over qb.
// Fixed-offset softmax soundness: RMS norm gives ||q||,||k|| <= sqrt(128)
// strictly, so |s| <= 5*sqrt(128) = 56.6, exp(s) <= 3.7e24, l <= 7.6e27,
// o <= ~5e28 — all within fp32/bf16 range; o/l identical to flash softmax.
__global__ __launch_bounds__(256, 4) void attn_kernel(
    __hip_bfloat16* __restrict__ qb,        // [B][T][NH*HD] -> overwritten
    const __hip_bfloat16* __restrict__ kb,  // [B][T][NKV*HD]
    const __hip_bfloat16* __restrict__ vt)  // [B][NKV][HD][T]
{
  const int tid  = threadIdx.x;
  const int wave = tid >> 6;
  const int lane = tid & 63;
  const int qd = lane >> 4, ln = lane & 15;
  const int qt = (gridDim.x - 1) - blockIdx.x;   // heavy blocks first
  const int h  = blockIdx.y;
  const int b  = blockIdx.z;
  const int hk = h >> 2;
  const int q0 = qt * 64;
  const int qw = q0 + wave * 16;

  __hip_bfloat16* Qp = qb + (size_t)(b*TSEQ)*CDIM + h*HDIM;
  const __hip_bfloat16* K = kb + (size_t)(b*TSEQ)*KVC + hk*HDIM;
  const __hip_bfloat16* V = vt + ((size_t)(b*NKV + hk)*HDIM)*TSEQ;

  __shared__ __align__(16) __hip_bfloat16 Ks[64*128];    // [t][d], swizzled
  __shared__ __align__(16) __hip_bfloat16 Vs[128*64];    // [d][t], swizzled
  __shared__ __align__(16) __hip_bfloat16 Pb[4*16*64];   // per-wave P, swizzled

  // Q fragments (A-layout): m=ln, k = kc*32 + qd*8
  bf16x8 qfr[4];
#pragma unroll
  for (int kc = 0; kc < 4; ++kc)
    qfr[kc] = *(const bf16x8*)&Qp[(size_t)(qw + ln)*CDIM + kc*32 + qd*8];

  f32x4 o[8] = {};
  float lacc[4] = {0.f, 0.f, 0.f, 0.f};

  const int ktiles = qt + 1;
  for (int kt = 0; kt < ktiles; ++kt) {
    const int t0 = kt * 64;
    __syncthreads();   // prior tile's LDS reads complete
    // stage K tile [64][128]  (round-4 validated inline staging)
#pragma unroll
    for (int i = 0; i < 4; ++i) {
      int e = (i*256 + tid) * 8;
      int row = e >> 7, col = e & 127;
      *(bf16x8*)&Ks[swz128(row, col)] = *(const bf16x8*)&K[(size_t)(t0 + row)*KVC + col];
    }
    // stage V tile [128][64]
#pragma unroll
    for (int i = 0; i < 4; ++i) {
      int e = (i*256 + tid) * 8;
      int row = e >> 6, col = e & 63;
      *(bf16x8*)&Vs[swz64(row, col)] = *(const bf16x8*)&V[(size_t)row*TSEQ + t0 + col];
    }
    __syncthreads();

    // S = Q K^T : 16 rows x 64 cols per wave
    f32x4 s[4] = {};
#pragma unroll
    for (int nt = 0; nt < 4; ++nt) {
#pragma unroll
      for (int kc = 0; kc < 4; ++kc) {
        bf16x8 kfr = *(const bf16x8*)&Ks[swz128(nt*16 + ln, kc*32 + qd*8)];
        s[nt] = mfma16(qfr[kc], kfr, s[nt]);
      }
    }
    if (kt == qt) {  // diagonal: causal mask
#pragma unroll
      for (int nt = 0; nt < 4; ++nt)
#pragma unroll
        for (int r = 0; r < 4; ++r) {
          int row = qw + qd*4 + r;
          int col = t0 + nt*16 + ln;
          if (col > row) s[nt][r] = -1.0e30f;
        }
    }
    // fixed-offset softmax: p = exp(s); defer the l reduction to the end
#pragma unroll
    for (int nt = 0; nt < 4; ++nt)
#pragma unroll
      for (int r = 0; r < 4; ++r)
        s[nt][r] = __expf(s[nt][r]);
#pragma unroll
    for (int r = 0; r < 4; ++r)
      lacc[r] += (s[0][r] + s[1][r]) + (s[2][r] + s[3][r]);

    // P (C-layout) -> wave-private LDS -> A-layout (validated no-barrier)
    __hip_bfloat16* Pw = &Pb[wave*1024];
#pragma unroll
    for (int nt = 0; nt < 4; ++nt)
#pragma unroll
      for (int r = 0; r < 4; ++r)
        Pw[swz64(qd*4 + r, nt*16 + ln)] = __float2bfloat16(s[nt][r]);
    bf16x8 pa[2];
#pragma unroll
    for (int kc = 0; kc < 2; ++kc)
      pa[kc] = *(const bf16x8*)&Pw[swz64(ln, kc*32 + qd*8)];
#pragma unroll
    for (int dt = 0; dt < 8; ++dt) {
#pragma unroll
      for (int kc = 0; kc < 2; ++kc) {
        bf16x8 vf = *(const bf16x8*)&Vs[swz64(dt*16 + ln, kc*32 + qd*8)];
        o[dt] = mfma16(pa[kc], vf, o[dt]);
      }
    }
  }

  // final l reduction (once): 16-lane group of this quad holds the row
  float inv[4];
#pragma unroll
  for (int r = 0; r < 4; ++r) {
    float lr = lacc[r];
    lr += __shfl_xor(lr, 1);
    lr += __shfl_xor(lr, 2);
    lr += __shfl_xor(lr, 4);
    lr += __shfl_xor(lr, 8);
    inv[r] = 1.0f / lr;
  }

  // coalesced epilogue via LDS (reuse Ks; wave-private 16x128 region),
  // hardened with a barrier between write and readback.
  __syncthreads();   // everyone done reading Ks/Vs
  __hip_bfloat16* Ow = &Ks[wave*2048];
#pragma unroll
  for (int dt = 0; dt < 8; ++dt)
#pragma unroll
    for (int r = 0; r < 4; ++r)
      Ow[(qd*4 + r)*128 + dt*16 + ln] = __float2bfloat16(o[dt][r] * inv[r]);
  __syncthreads();   // make writes visible to all lanes before readback
#pragma unroll
  for (int pass = 0; pass < 4; ++pass) {
    int row = pass*4 + qd;           // 0..15 within wave's q-rows
    bf16x8 val = *(const bf16x8*)&Ow[row*128 + ln*8];
    int q = qw + row;
    *(bf16x8*)&qb[((size_t)(b*TSEQ + q))*CDIM + h*HDIM + ln*8] = val;
  }
}

extern "C" void kernel_launch(void* const* d_in, const int* in_sizes, int n_in,
                              void* d_out, int out_size, void* d_ws, size_t ws_size,
                              hipStream_t stream) {
  char* ws = (char*)d_ws;
  size_t off = 0;
  auto alloc = [&](size_t bytes) { char* p = ws + off; off += (bytes + 255) & ~(size_t)255; return p; };

  int* flag = (int*)alloc(256);
  __hip_bfloat16* xb  = (__hip_bfloat16*)alloc((size_t)MROWS*CDIM*2);
  __hip_bfloat16* wqb = (__hip_bfloat16*)alloc((size_t)CDIM*CDIM*2);
  __hip_bfloat16* wkb = (__hip_bfloat16*)alloc((size_t)KVC*CDIM*2);
  __hip_bfloat16* wvb = (__hip_bfloat16*)alloc((size_t)KVC*CDIM*2);
  __hip_bfloat16* wob = (__hip_bfloat16*)alloc((size_t)CDIM*CDIM*2);
  __hip_bfloat16* gb  = (__hip_bfloat16*)alloc(256);
  __hip_bfloat16* qb  = (__hip_bfloat16*)alloc((size_t)MROWS*CDIM*2);
  __hip_bfloat16* kb  = (__hip_bfloat16*)alloc((size_t)MROWS*KVC*2);
  __hip_bfloat16* vb  = (__hip_bfloat16*)alloc((size_t)MROWS*KVC*2);
  __hip_bfloat16* vt  = (__hip_bfloat16*)alloc((size_t)MROWS*KVC*2);

  canary<<<1, 256, 0, stream>>>(d_in[0], flag);

  canonize<<<(MROWS*CDIM)/(8*256), 256, 0, stream>>>(d_in[0], xb,  MROWS*CDIM, flag);
  canonize<<<(CDIM*CDIM)/(8*256),  256, 0, stream>>>(d_in[1], wqb, CDIM*CDIM,  flag);
  canonize<<<(KVC*CDIM)/(8*256),   256, 0, stream>>>(d_in[2], wkb, KVC*CDIM,   flag);
  canonize<<<(KVC*CDIM)/(8*256),   256, 0, stream>>>(d_in[3], wvb, KVC*CDIM,   flag);
  canonize<<<(CDIM*CDIM)/(8*256),  256, 0, stream>>>(d_in[4], wob, CDIM*CDIM,  flag);
  canonize<<<1, 256, 0, stream>>>(d_in[5], gb, NH, flag);

  gemm_bt<<<dim3(CDIM/128, MROWS/128), 256, 0, stream>>>(xb, wqb, qb, MROWS, CDIM, CDIM);
  gemm_bt<<<dim3(KVC/128,  MROWS/128), 256, 0, stream>>>(xb, wkb, kb, MROWS, KVC, CDIM);
  gemm_bt<<<dim3(KVC/128,  MROWS/128), 256, 0, stream>>>(xb, wvb, vb, MROWS, KVC, CDIM);

  int nwaves = MROWS*NH + MROWS*NKV;
  prep_qk<<<nwaves/4, 256, 0, stream>>>(qb, kb, gb);

  transpose_v<<<dim3(MROWS/32, KVC/32), 256, 0, stream>>>(vb, vt);

  attn_kernel<<<dim3(TSEQ/64, NH, BATCH), 256, 0, stream>>>(qb, kb, vt);

  gemm_out<<<dim3(CDIM/128, MROWS/128), 256, 0, stream>>>(qb, wob, d_out, MROWS, CDIM, CDIM, flag);
}

// Round 7
// 382.618 us; speedup vs baseline: 1.5139x; 1.1932x over previous
//
#include <hip/hip_runtime.h>
#include <hip/hip_bf16.h>

#define TSEQ 2048
#define CDIM 2048
#define NH   16
#define NKV  4
#define HDIM 128
#define BATCH 2
#define MROWS (BATCH*TSEQ)   // 4096
#define KVC   (NKV*HDIM)     // 512

typedef short bf16x8 __attribute__((ext_vector_type(8)));
typedef float f32x4  __attribute__((ext_vector_type(4)));

typedef const __attribute__((address_space(1))) void* gptr_t;
typedef __attribute__((address_space(3))) void* sptr_t;

__device__ inline void async16(const __hip_bfloat16* g, __hip_bfloat16* l) {
  __builtin_amdgcn_global_load_lds((gptr_t)g, (sptr_t)l, 16, 0, 0);
}

__device__ inline f32x4 mfma16(bf16x8 a, bf16x8 b, f32x4 c) {
  return __builtin_amdgcn_mfma_f32_16x16x32_bf16(a, b, c, 0, 0, 0);
}

__device__ inline float bfbits2f(unsigned short u) {
  return __uint_as_float(((unsigned)u) << 16);
}

// LDS XOR-swizzles: break row-stride bank aliasing for 16B fragment access.
__device__ inline int swz128(int row, int col) {  // rows of 128 bf16
  return row*128 + (((col >> 3) ^ (row & 15)) << 3) + (col & 7);
}
__device__ inline int swz64(int row, int col) {   // rows of 64 bf16
  return row*64 + ((((col >> 3) ^ row) & 7) << 3) + (col & 7);
}

// ---- dtype canary: inputs bf16 (flag=1) or f32 (flag=0) ----
__global__ void canary(const void* __restrict__ x, int* __restrict__ flag) {
  __shared__ int cnt[256];
  int tid = threadIdx.x;
  const unsigned short* u = (const unsigned short*)x;
  int c = 0;
#pragma unroll
  for (int i = 0; i < 4; ++i) {
    float a = fabsf(bfbits2f(u[(tid*4 + i)*2]));
    if (a >= 1e-6f && a <= 1e3f) c++;
  }
  cnt[tid] = c;
  __syncthreads();
  for (int s = 128; s > 0; s >>= 1) {
    if (tid < s) cnt[tid] += cnt[tid + s];
    __syncthreads();
  }
  if (tid == 0) *flag = (cnt[0] > 512) ? 1 : 0;
}

// ---- canonize: known-bf16 copy of an input tensor ----
__global__ __launch_bounds__(256) void canonize(
    const void* __restrict__ src, __hip_bfloat16* __restrict__ dst,
    int n, const int* __restrict__ flag) {
  int base = (blockIdx.x * 256 + threadIdx.x) * 8;
  if (base >= n) return;
  if (*flag) {
    *(bf16x8*)&dst[base] = *(const bf16x8*)((const __hip_bfloat16*)src + base);
  } else {
    const float* s = (const float*)src + base;
#pragma unroll
    for (int j = 0; j < 8; ++j) dst[base + j] = __float2bfloat16(s[j]);
  }
}

// C[m,n] = sum_k A[m,k]*B[n,k]; m97-style async staging.
__global__ __launch_bounds__(256, 2) void gemm_bt(
    const __hip_bfloat16* __restrict__ A,
    const __hip_bfloat16* __restrict__ B,
    __hip_bfloat16* __restrict__ C,
    int M, int N, int K)
{
  __shared__ __align__(16) __hip_bfloat16 As[128*32];
  __shared__ __align__(16) __hip_bfloat16 Bs[128*32];
  const int tid  = threadIdx.x;
  const int wave = tid >> 6;
  const int lane = tid & 63;
  const int qd   = lane >> 4;
  const int ln   = lane & 15;
  const int m0   = blockIdx.y * 128;
  const int n0   = blockIdx.x * 128;
  const int wm   = (wave >> 1) * 64;
  const int wn   = (wave & 1) * 64;

  f32x4 acc[4][4] = {};

  for (int k0 = 0; k0 < K; k0 += 32) {
    __syncthreads();
#pragma unroll
    for (int r = 0; r < 2; ++r) {
      int e   = (r*256 + tid) * 8;
      int row = e >> 5;
      int col = e & 31;
      async16(&A[(size_t)(m0+row)*K + k0 + col], &As[(size_t)(r*256 + wave*64)*8]);
      async16(&B[(size_t)(n0+row)*K + k0 + col], &Bs[(size_t)(r*256 + wave*64)*8]);
    }
    __syncthreads();
    bf16x8 af[4], bfr[4];
#pragma unroll
    for (int i = 0; i < 4; ++i)
      af[i] = *(const bf16x8*)&As[(wm + i*16 + ln)*32 + qd*8];
#pragma unroll
    for (int j = 0; j < 4; ++j)
      bfr[j] = *(const bf16x8*)&Bs[(wn + j*16 + ln)*32 + qd*8];
#pragma unroll
    for (int i = 0; i < 4; ++i)
#pragma unroll
      for (int j = 0; j < 4; ++j)
        acc[i][j] = mfma16(af[i], bfr[j], acc[i][j]);
  }
#pragma unroll
  for (int i = 0; i < 4; ++i)
#pragma unroll
    for (int j = 0; j < 4; ++j) {
      int row = m0 + wm + i*16 + qd*4;
      int col = n0 + wn + j*16 + ln;
#pragma unroll
      for (int r = 0; r < 4; ++r)
        C[(size_t)(row + r)*N + col] = __float2bfloat16(acc[i][j][r]);
    }
}

// Same GEMM; epilogue dtype per flag (d_out matches input dtype).
__global__ __launch_bounds__(256, 2) void gemm_out(
    const __hip_bfloat16* __restrict__ A,
    const __hip_bfloat16* __restrict__ B,
    void* __restrict__ C,
    int M, int N, int K, const int* __restrict__ flag)
{
  __shared__ __align__(16) __hip_bfloat16 As[128*32];
  __shared__ __align__(16) __hip_bfloat16 Bs[128*32];
  const int tid  = threadIdx.x;
  const int wave = tid >> 6;
  const int lane = tid & 63;
  const int qd   = lane >> 4;
  const int ln   = lane & 15;
  const int m0   = blockIdx.y * 128;
  const int n0   = blockIdx.x * 128;
  const int wm   = (wave >> 1) * 64;
  const int wn   = (wave & 1) * 64;

  f32x4 acc[4][4] = {};

  for (int k0 = 0; k0 < K; k0 += 32) {
    __syncthreads();
#pragma unroll
    for (int r = 0; r < 2; ++r) {
      int e   = (r*256 + tid) * 8;
      int row = e >> 5;
      int col = e & 31;
      async16(&A[(size_t)(m0+row)*K + k0 + col], &As[(size_t)(r*256 + wave*64)*8]);
      async16(&B[(size_t)(n0+row)*K + k0 + col], &Bs[(size_t)(r*256 + wave*64)*8]);
    }
    __syncthreads();
    bf16x8 af[4], bfr[4];
#pragma unroll
    for (int i = 0; i < 4; ++i)
      af[i] = *(const bf16x8*)&As[(wm + i*16 + ln)*32 + qd*8];
#pragma unroll
    for (int j = 0; j < 4; ++j)
      bfr[j] = *(const bf16x8*)&Bs[(wn + j*16 + ln)*32 + qd*8];
#pragma unroll
    for (int i = 0; i < 4; ++i)
#pragma unroll
      for (int j = 0; j < 4; ++j)
        acc[i][j] = mfma16(af[i], bfr[j], acc[i][j]);
  }
  const bool isbf = (*flag != 0);
#pragma unroll
  for (int i = 0; i < 4; ++i)
#pragma unroll
    for (int j = 0; j < 4; ++j) {
      int row = m0 + wm + i*16 + qd*4;
      int col = n0 + wn + j*16 + ln;
#pragma unroll
      for (int r = 0; r < 4; ++r) {
        if (isbf) ((__hip_bfloat16*)C)[(size_t)(row + r)*N + col] = __float2bfloat16(acc[i][j][r]);
        else      ((float*)C)[(size_t)(row + r)*N + col] = acc[i][j][r];
      }
    }
}

// RMSNorm + RoPE + (gain/sqrt(HD) for q), in place on bf16 buffers.
__global__ __launch_bounds__(256) void prep_qk(
    __hip_bfloat16* __restrict__ qb,   // [4096][2048]
    __hip_bfloat16* __restrict__ kb,   // [4096][512]
    const __hip_bfloat16* __restrict__ gain)
{
  int wid  = blockIdx.x * 4 + (threadIdx.x >> 6);
  int lane = threadIdx.x & 63;
  bool isq = wid < MROWS*NH;
  int m, h;
  __hip_bfloat16* p;
  if (isq) { m = wid >> 4; h = wid & 15; p = qb + (size_t)m*CDIM + h*HDIM; }
  else     { int w2 = wid - MROWS*NH; m = w2 >> 2; h = w2 & 3; p = kb + (size_t)m*KVC + h*HDIM; }

  ushort2 raw = *(const ushort2*)((const unsigned short*)p + 2*lane);
  float e = bfbits2f(raw.x), o = bfbits2f(raw.y);
  float ss = e*e + o*o;
#pragma unroll
  for (int off = 32; off >= 1; off >>= 1) ss += __shfl_xor(ss, off);
  float rms = rsqrtf(ss * (1.0f/128.0f) + 1.1920928955078125e-07f);
  e *= rms; o *= rms;

  float theta = exp2f(-(float)(2*lane) * (1.0f/128.0f) * 13.287712379549449f);
  int t = m & (TSEQ-1);
  float fr = (float)t * theta;
  float c = cosf(fr), s = sinf(fr);
  float re = e*c - o*s;
  float ro = e*s + o*c;

  if (isq) {
    float g = bfbits2f(*(const unsigned short*)&gain[h]) * 0.08838834764831845f;
    re *= g; ro *= g;
  }
  p[2*lane]   = __float2bfloat16(re);
  p[2*lane+1] = __float2bfloat16(ro);
}

// v_bf [4096][512] -> vt [B][NKV][HDIM][TSEQ]
__global__ __launch_bounds__(256) void transpose_v(
    const __hip_bfloat16* __restrict__ v, __hip_bfloat16* __restrict__ vt)
{
  __shared__ __hip_bfloat16 tile[32][34];
  int tx = threadIdx.x & 31;
  int ty = threadIdx.x >> 5;
  int r0 = blockIdx.x * 32;
  int c0 = blockIdx.y * 32;
#pragma unroll
  for (int i = 0; i < 4; ++i)
    tile[ty + i*8][tx] = v[(size_t)(r0 + ty + i*8)*KVC + c0 + tx];
  __syncthreads();
  int b = r0 >> 11;
  int t = r0 & (TSEQ-1);
  int hk = c0 >> 7;
  int d0 = c0 & (HDIM-1);
#pragma unroll
  for (int i = 0; i < 4; ++i) {
    int d = d0 + ty + i*8;
    vt[((size_t)((b*NKV + hk)*HDIM + d))*TSEQ + t + tx] = tile[tx][ty + i*8];
  }
}

// Flash attention v5: diagonal-paired q-tiles (uniform 33-tile blocks),
// async global_load_lds staging with inverse-swizzled source, split-phase
// pipeline (V loads overlap QK, K loads overlap PV; each barrier drains
// only loads issued a full compute-phase earlier). Fixed-offset softmax
// (|s|<=56.6 proven by RMS-norm bound). In place over qb.
__global__ __launch_bounds__(256, 2) void attn_kernel(
    __hip_bfloat16* __restrict__ qb,        // [B][T][NH*HD] -> overwritten
    const __hip_bfloat16* __restrict__ kb,  // [B][T][NKV*HD]
    const __hip_bfloat16* __restrict__ vt)  // [B][NKV][HD][T]
{
  const int tid  = threadIdx.x;
  const int wave = tid >> 6;
  const int lane = tid & 63;
  const int qd = lane >> 4, ln = lane & 15;
  const int p  = blockIdx.x;     // pair index 0..15 -> q-tiles {p, 31-p}
  const int h  = blockIdx.y;
  const int b  = blockIdx.z;
  const int hk = h >> 2;

  const __hip_bfloat16* K = kb + (size_t)(b*TSEQ)*KVC + hk*HDIM;
  const __hip_bfloat16* V = vt + ((size_t)(b*NKV + hk)*HDIM)*TSEQ;

  __shared__ __align__(16) __hip_bfloat16 Ks[64*128];    // [t][d], swizzled
  __shared__ __align__(16) __hip_bfloat16 Vs[128*64];    // [d][t], swizzled
  __shared__ __align__(16) __hip_bfloat16 Pb[4*16*64];   // per-wave P, swizzled

  // async stage helpers: LDS dest is lane-linear (base + lane*16); the
  // swizzle is applied on the SOURCE index (chunk c holds global chunk
  // c ^ (row & mask)), so compute-side swz128/swz64 reads stay valid.
  auto issueK = [&](int t0) {
#pragma unroll
    for (int i = 0; i < 4; ++i) {
      int c = i*256 + tid;             // chunk 0..1023; 16 chunks/row
      int row = c >> 4, cc = c & 15;
      int gcc = cc ^ (row & 15);
      async16(&K[(size_t)(t0 + row)*KVC + gcc*8], &Ks[(i*256 + wave*64)*8]);
    }
  };
  auto issueV = [&](int t0) {
#pragma unroll
    for (int i = 0; i < 4; ++i) {
      int c = i*256 + tid;             // chunk 0..1023; 8 chunks/row
      int row = c >> 3, cc = c & 7;
      int gcc = cc ^ (row & 7);
      async16(&V[(size_t)row*TSEQ + t0 + gcc*8], &Vs[(i*256 + wave*64)*8]);
    }
  };

#pragma unroll 1
  for (int seg = 0; seg < 2; ++seg) {
    const int qt = seg ? (31 - p) : p;
    const int q0 = qt * 64;
    const int qw = q0 + wave * 16;

    // Q fragments (A-layout): m=ln, k = kc*32 + qd*8
    bf16x8 qfr[4];
#pragma unroll
    for (int kc = 0; kc < 4; ++kc)
      qfr[kc] = *(const bf16x8*)&qb[((size_t)(b*TSEQ + qw + ln))*CDIM + h*HDIM + kc*32 + qd*8];

    f32x4 o[8] = {};
    float lacc[4] = {0.f, 0.f, 0.f, 0.f};

    __syncthreads();          // Ks free (prev segment's epilogue readback done)
    issueK(0);
    __syncthreads();          // drain K[0]

#pragma unroll 1
    for (int kt = 0; kt <= qt; ++kt) {
      const int t0 = kt * 64;
      issueV(t0);             // Vs free: PV[kt-1] done by all at loop-end sync

      // QK^T from Ks (overlaps V flight)
      f32x4 s[4] = {};
#pragma unroll
      for (int nt = 0; nt < 4; ++nt) {
#pragma unroll
        for (int kc = 0; kc < 4; ++kc) {
          bf16x8 kfr = *(const bf16x8*)&Ks[swz128(nt*16 + ln, kc*32 + qd*8)];
          s[nt] = mfma16(qfr[kc], kfr, s[nt]);
        }
      }
      if (kt == qt) {  // diagonal: causal mask
#pragma unroll
        for (int nt = 0; nt < 4; ++nt)
#pragma unroll
          for (int r = 0; r < 4; ++r) {
            int row = qw + qd*4 + r;
            int col = t0 + nt*16 + ln;
            if (col > row) s[nt][r] = -1.0e30f;
          }
      }
      // fixed-offset softmax: p = exp(s), defer l reduction
#pragma unroll
      for (int nt = 0; nt < 4; ++nt)
#pragma unroll
        for (int r = 0; r < 4; ++r)
          s[nt][r] = __expf(s[nt][r]);
#pragma unroll
      for (int r = 0; r < 4; ++r)
        lacc[r] += (s[0][r] + s[1][r]) + (s[2][r] + s[3][r]);

      // P (C-layout) -> wave-private LDS -> A-layout (no barrier)
      __hip_bfloat16* Pw = &Pb[wave*1024];
#pragma unroll
      for (int nt = 0; nt < 4; ++nt)
#pragma unroll
        for (int r = 0; r < 4; ++r)
          Pw[swz64(qd*4 + r, nt*16 + ln)] = __float2bfloat16(s[nt][r]);
      bf16x8 pa[2];
#pragma unroll
      for (int kc = 0; kc < 2; ++kc)
        pa[kc] = *(const bf16x8*)&Pw[swz64(ln, kc*32 + qd*8)];

      __syncthreads();        // drain V[kt]; all waves done QK -> Ks free
      if (kt < qt) issueK(t0 + 64);   // overlaps PV

      // PV from Vs
#pragma unroll
      for (int dt = 0; dt < 8; ++dt) {
#pragma unroll
        for (int kc = 0; kc < 2; ++kc) {
          bf16x8 vf = *(const bf16x8*)&Vs[swz64(dt*16 + ln, kc*32 + qd*8)];
          o[dt] = mfma16(pa[kc], vf, o[dt]);
        }
      }
      __syncthreads();        // drain K[kt+1]; all waves done PV -> Vs free
    }

    // final l reduction (once per segment)
    float inv[4];
#pragma unroll
    for (int r = 0; r < 4; ++r) {
      float lr = lacc[r];
      lr += __shfl_xor(lr, 1);
      lr += __shfl_xor(lr, 2);
      lr += __shfl_xor(lr, 4);
      lr += __shfl_xor(lr, 8);
      inv[r] = 1.0f / lr;
    }

    // coalesced epilogue via LDS (reuse Ks; wave-private 16x128 region)
    __hip_bfloat16* Ow = &Ks[wave*2048];
#pragma unroll
    for (int dt = 0; dt < 8; ++dt)
#pragma unroll
      for (int r = 0; r < 4; ++r)
        Ow[(qd*4 + r)*128 + dt*16 + ln] = __float2bfloat16(o[dt][r] * inv[r]);
    __syncthreads();          // writes visible before readback
#pragma unroll
    for (int pass = 0; pass < 4; ++pass) {
      int row = pass*4 + qd;
      bf16x8 val = *(const bf16x8*)&Ow[row*128 + ln*8];
      int q = qw + row;
      *(bf16x8*)&qb[((size_t)(b*TSEQ + q))*CDIM + h*HDIM + ln*8] = val;
    }
  }
}

extern "C" void kernel_launch(void* const* d_in, const int* in_sizes, int n_in,
                              void* d_out, int out_size, void* d_ws, size_t ws_size,
                              hipStream_t stream) {
  char* ws = (char*)d_ws;
  size_t off = 0;
  auto alloc = [&](size_t bytes) { char* p = ws + off; off += (bytes + 255) & ~(size_t)255; return p; };

  int* flag = (int*)alloc(256);
  __hip_bfloat16* xb  = (__hip_bfloat16*)alloc((size_t)MROWS*CDIM*2);
  __hip_bfloat16* wqb = (__hip_bfloat16*)alloc((size_t)CDIM*CDIM*2);
  __hip_bfloat16* wkb = (__hip_bfloat16*)alloc((size_t)KVC*CDIM*2);
  __hip_bfloat16* wvb = (__hip_bfloat16*)alloc((size_t)KVC*CDIM*2);
  __hip_bfloat16* wob = (__hip_bfloat16*)alloc((size_t)CDIM*CDIM*2);
  __hip_bfloat16* gb  = (__hip_bfloat16*)alloc(256);
  __hip_bfloat16* qb  = (__hip_bfloat16*)alloc((size_t)MROWS*CDIM*2);
  __hip_bfloat16* kb  = (__hip_bfloat16*)alloc((size_t)MROWS*KVC*2);
  __hip_bfloat16* vb  = (__hip_bfloat16*)alloc((size_t)MROWS*KVC*2);
  __hip_bfloat16* vt  = (__hip_bfloat16*)alloc((size_t)MROWS*KVC*2);

  canary<<<1, 256, 0, stream>>>(d_in[0], flag);

  canonize<<<(MROWS*CDIM)/(8*256), 256, 0, stream>>>(d_in[0], xb,  MROWS*CDIM, flag);
  canonize<<<(CDIM*CDIM)/(8*256),  256, 0, stream>>>(d_in[1], wqb, CDIM*CDIM,  flag);
  canonize<<<(KVC*CDIM)/(8*256),   256, 0, stream>>>(d_in[2], wkb, KVC*CDIM,   flag);
  canonize<<<(KVC*CDIM)/(8*256),   256, 0, stream>>>(d_in[3], wvb, KVC*CDIM,   flag);
  canonize<<<(CDIM*CDIM)/(8*256),  256, 0, stream>>>(d_in[4], wob, CDIM*CDIM,  flag);
  canonize<<<1, 256, 0, stream>>>(d_in[5], gb, NH, flag);

  gemm_bt<<<dim3(CDIM/128, MROWS/128), 256, 0, stream>>>(xb, wqb, qb, MROWS, CDIM, CDIM);
  gemm_bt<<<dim3(KVC/128,  MROWS/128), 256, 0, stream>>>(xb, wkb, kb, MROWS, KVC, CDIM);
  gemm_bt<<<dim3(KVC/128,  MROWS/128), 256, 0, stream>>>(xb, wvb, vb, MROWS, KVC, CDIM);

  int nwaves = MROWS*NH + MROWS*NKV;
  prep_qk<<<nwaves/4, 256, 0, stream>>>(qb, kb, gb);

  transpose_v<<<dim3(MROWS/32, KVC/32), 256, 0, stream>>>(vb, vt);

  attn_kernel<<<dim3(TSEQ/128, NH, BATCH), 256, 0, stream>>>(qb, kb, vt);

  gemm_out<<<dim3(CDIM/128, MROWS/128), 256, 0, stream>>>(qb, wob, d_out, MROWS, CDIM, CDIM, flag);
}

// Round 9
// 305.766 us; speedup vs baseline: 1.8944x; 1.2513x over previous
//
#include <hip/hip_runtime.h>
#include <hip/hip_bf16.h>

#define TSEQ 2048
#define CDIM 2048
#define NH   16
#define NKV  4
#define HDIM 128
#define BATCH 2
#define MROWS (BATCH*TSEQ)   // 4096
#define KVC   (NKV*HDIM)     // 512
#define QKVC  (CDIM + 2*KVC) // 3072: fused qkv row stride

typedef short bf16x8 __attribute__((ext_vector_type(8)));
typedef float f32x4  __attribute__((ext_vector_type(4)));

typedef const __attribute__((address_space(1))) void* gptr_t;
typedef __attribute__((address_space(3))) void* sptr_t;

__device__ inline void async16(const __hip_bfloat16* g, __hip_bfloat16* l) {
  __builtin_amdgcn_global_load_lds((gptr_t)g, (sptr_t)l, 16, 0, 0);
}

__device__ inline f32x4 mfma16(bf16x8 a, bf16x8 b, f32x4 c) {
  return __builtin_amdgcn_mfma_f32_16x16x32_bf16(a, b, c, 0, 0, 0);
}

__device__ inline float bfbits2f(unsigned short u) {
  return __uint_as_float(((unsigned)u) << 16);
}

// LDS XOR-swizzles: break row-stride bank aliasing for 16B fragment access.
__device__ inline int swz128(int row, int col) {  // rows of 128 bf16
  return row*128 + (((col >> 3) ^ (row & 15)) << 3) + (col & 7);
}
__device__ inline int swz64(int row, int col) {   // rows of 64 bf16
  return row*64 + ((((col >> 3) ^ row) & 7) << 3) + (col & 7);
}

// ---- dtype canary: inputs bf16 (flag=1) or f32 (flag=0) ----
__global__ void canary(const void* __restrict__ x, int* __restrict__ flag) {
  __shared__ int cnt[256];
  int tid = threadIdx.x;
  const unsigned short* u = (const unsigned short*)x;
  int c = 0;
#pragma unroll
  for (int i = 0; i < 4; ++i) {
    float a = fabsf(bfbits2f(u[(tid*4 + i)*2]));
    if (a >= 1e-6f && a <= 1e3f) c++;
  }
  cnt[tid] = c;
  __syncthreads();
  for (int s = 128; s > 0; s >>= 1) {
    if (tid < s) cnt[tid] += cnt[tid + s];
    __syncthreads();
  }
  if (tid == 0) *flag = (cnt[0] > 512) ? 1 : 0;
}

// ---- canonize ALL inputs in one launch; Wq/Wk/Wv land contiguously ----
// Segments (2048-elem blocks): x:4096 | Wq:2048 | Wk:512 | Wv:512 | Wo:2048 | gain:1
__global__ __launch_bounds__(256) void canonize_all(
    const void* __restrict__ xs,  const void* __restrict__ wqs,
    const void* __restrict__ wks, const void* __restrict__ wvs,
    const void* __restrict__ wos, const void* __restrict__ gs,
    __hip_bfloat16* __restrict__ xd,   // [4096][2048]
    __hip_bfloat16* __restrict__ wqkv, // [3072][2048] (Wq;Wk;Wv rows)
    __hip_bfloat16* __restrict__ wod,  // [2048][2048]
    __hip_bfloat16* __restrict__ gd,   // [16]
    const int* __restrict__ flag)
{
  int blk = blockIdx.x;
  const void* src; __hip_bfloat16* dst; int base, n;
  if      (blk < 4096) { src = xs;  dst = xd;                base = blk;        n = MROWS*CDIM; }
  else if (blk < 6144) { src = wqs; dst = wqkv;              base = blk - 4096; n = CDIM*CDIM; }
  else if (blk < 6656) { src = wks; dst = wqkv + (size_t)CDIM*CDIM;            base = blk - 6144; n = KVC*CDIM; }
  else if (blk < 7168) { src = wvs; dst = wqkv + (size_t)(CDIM+KVC)*CDIM;      base = blk - 6656; n = KVC*CDIM; }
  else if (blk < 9216) { src = wos; dst = wod;               base = blk - 7168; n = CDIM*CDIM; }
  else                 { src = gs;  dst = gd;                base = 0;          n = NH; }
  int idx = base*2048 + threadIdx.x*8;
  if (idx >= n) return;
  if (*flag) {
    *(bf16x8*)&dst[idx] = *(const bf16x8*)((const __hip_bfloat16*)src + idx);
  } else {
    const float* s = (const float*)src + idx;
#pragma unroll
    for (int j = 0; j < 8; ++j) dst[idx + j] = __float2bfloat16(s[j]);
  }
}

// C[m,n] = sum_k A[m,k]*B[n,k]; A row stride lda. m97-style async staging.
__global__ __launch_bounds__(256, 2) void gemm_bt(
    const __hip_bfloat16* __restrict__ A,
    const __hip_bfloat16* __restrict__ B,
    __hip_bfloat16* __restrict__ C,
    int M, int N, int K, int lda)
{
  __shared__ __align__(16) __hip_bfloat16 As[128*32];
  __shared__ __align__(16) __hip_bfloat16 Bs[128*32];
  const int tid  = threadIdx.x;
  const int wave = tid >> 6;
  const int lane = tid & 63;
  const int qd   = lane >> 4;
  const int ln   = lane & 15;
  const int m0   = blockIdx.y * 128;
  const int n0   = blockIdx.x * 128;
  const int wm   = (wave >> 1) * 64;
  const int wn   = (wave & 1) * 64;

  f32x4 acc[4][4] = {};

  for (int k0 = 0; k0 < K; k0 += 32) {
    __syncthreads();
#pragma unroll
    for (int r = 0; r < 2; ++r) {
      int e   = (r*256 + tid) * 8;
      int row = e >> 5;
      int col = e & 31;
      async16(&A[(size_t)(m0+row)*lda + k0 + col], &As[(size_t)(r*256 + wave*64)*8]);
      async16(&B[(size_t)(n0+row)*K   + k0 + col], &Bs[(size_t)(r*256 + wave*64)*8]);
    }
    __syncthreads();
    bf16x8 af[4], bfr[4];
#pragma unroll
    for (int i = 0; i < 4; ++i)
      af[i] = *(const bf16x8*)&As[(wm + i*16 + ln)*32 + qd*8];
#pragma unroll
    for (int j = 0; j < 4; ++j)
      bfr[j] = *(const bf16x8*)&Bs[(wn + j*16 + ln)*32 + qd*8];
#pragma unroll
    for (int i = 0; i < 4; ++i)
#pragma unroll
      for (int j = 0; j < 4; ++j)
        acc[i][j] = mfma16(af[i], bfr[j], acc[i][j]);
  }
#pragma unroll
  for (int i = 0; i < 4; ++i)
#pragma unroll
    for (int j = 0; j < 4; ++j) {
      int row = m0 + wm + i*16 + qd*4;
      int col = n0 + wn + j*16 + ln;
#pragma unroll
      for (int r = 0; r < 4; ++r)
        C[(size_t)(row + r)*N + col] = __float2bfloat16(acc[i][j][r]);
    }
}

// Same GEMM; epilogue dtype per flag (d_out matches input dtype).
__global__ __launch_bounds__(256, 2) void gemm_out(
    const __hip_bfloat16* __restrict__ A,
    const __hip_bfloat16* __restrict__ B,
    void* __restrict__ C,
    int M, int N, int K, int lda, const int* __restrict__ flag)
{
  __shared__ __align__(16) __hip_bfloat16 As[128*32];
  __shared__ __align__(16) __hip_bfloat16 Bs[128*32];
  const int tid  = threadIdx.x;
  const int wave = tid >> 6;
  const int lane = tid & 63;
  const int qd   = lane >> 4;
  const int ln   = lane & 15;
  const int m0   = blockIdx.y * 128;
  const int n0   = blockIdx.x * 128;
  const int wm   = (wave >> 1) * 64;
  const int wn   = (wave & 1) * 64;

  f32x4 acc[4][4] = {};

  for (int k0 = 0; k0 < K; k0 += 32) {
    __syncthreads();
#pragma unroll
    for (int r = 0; r < 2; ++r) {
      int e   = (r*256 + tid) * 8;
      int row = e >> 5;
      int col = e & 31;
      async16(&A[(size_t)(m0+row)*lda + k0 + col], &As[(size_t)(r*256 + wave*64)*8]);
      async16(&B[(size_t)(n0+row)*K   + k0 + col], &Bs[(size_t)(r*256 + wave*64)*8]);
    }
    __syncthreads();
    bf16x8 af[4], bfr[4];
#pragma unroll
    for (int i = 0; i < 4; ++i)
      af[i] = *(const bf16x8*)&As[(wm + i*16 + ln)*32 + qd*8];
#pragma unroll
    for (int j = 0; j < 4; ++j)
      bfr[j] = *(const bf16x8*)&Bs[(wn + j*16 + ln)*32 + qd*8];
#pragma unroll
    for (int i = 0; i < 4; ++i)
#pragma unroll
      for (int j = 0; j < 4; ++j)
        acc[i][j] = mfma16(af[i], bfr[j], acc[i][j]);
  }
  const bool isbf = (*flag != 0);
#pragma unroll
  for (int i = 0; i < 4; ++i)
#pragma unroll
    for (int j = 0; j < 4; ++j) {
      int row = m0 + wm + i*16 + qd*4;
      int col = n0 + wn + j*16 + ln;
#pragma unroll
      for (int r = 0; r < 4; ++r) {
        if (isbf) ((__hip_bfloat16*)C)[(size_t)(row + r)*N + col] = __float2bfloat16(acc[i][j][r]);
        else      ((float*)C)[(size_t)(row + r)*N + col] = acc[i][j][r];
      }
    }
}

// RMSNorm + RoPE + (gain/sqrt(HD) for q), in place on the fused qkv buffer.
__global__ __launch_bounds__(256) void prep_qk(
    __hip_bfloat16* __restrict__ qkv,  // [4096][3072]: q | k | v
    const __hip_bfloat16* __restrict__ gain)
{
  int wid  = blockIdx.x * 4 + (threadIdx.x >> 6);
  int lane = threadIdx.x & 63;
  bool isq = wid < MROWS*NH;
  int m, h;
  __hip_bfloat16* p;
  if (isq) { m = wid >> 4; h = wid & 15; p = qkv + (size_t)m*QKVC + h*HDIM; }
  else     { int w2 = wid - MROWS*NH; m = w2 >> 2; h = w2 & 3; p = qkv + (size_t)m*QKVC + CDIM + h*HDIM; }

  ushort2 raw = *(const ushort2*)((const unsigned short*)p + 2*lane);
  float e = bfbits2f(raw.x), o = bfbits2f(raw.y);
  float ss = e*e + o*o;
#pragma unroll
  for (int off = 32; off >= 1; off >>= 1) ss += __shfl_xor(ss, off);
  float rms = rsqrtf(ss * (1.0f/128.0f) + 1.1920928955078125e-07f);
  e *= rms; o *= rms;

  float theta = exp2f(-(float)(2*lane) * (1.0f/128.0f) * 13.287712379549449f);
  int t = m & (TSEQ-1);
  float fr = (float)t * theta;
  float c = cosf(fr), s = sinf(fr);
  float re = e*c - o*s;
  float ro = e*s + o*c;

  if (isq) {
    float g = bfbits2f(*(const unsigned short*)&gain[h]) * 0.08838834764831845f;
    re *= g; ro *= g;
  }
  p[2*lane]   = __float2bfloat16(re);
  p[2*lane+1] = __float2bfloat16(ro);
}

// v section of qkv [4096][3072] -> vt [B][NKV][HDIM][TSEQ]
__global__ __launch_bounds__(256) void transpose_v(
    const __hip_bfloat16* __restrict__ qkv, __hip_bfloat16* __restrict__ vt)
{
  __shared__ __hip_bfloat16 tile[32][34];
  int tx = threadIdx.x & 31;
  int ty = threadIdx.x >> 5;
  int r0 = blockIdx.x * 32;
  int c0 = blockIdx.y * 32;
#pragma unroll
  for (int i = 0; i < 4; ++i)
    tile[ty + i*8][tx] = qkv[(size_t)(r0 + ty + i*8)*QKVC + (CDIM + KVC) + c0 + tx];
  __syncthreads();
  int b = r0 >> 11;
  int t = r0 & (TSEQ-1);
  int hk = c0 >> 7;
  int d0 = c0 & (HDIM-1);
#pragma unroll
  for (int i = 0; i < 4; ++i) {
    int d = d0 + ty + i*8;
    vt[((size_t)((b*NKV + hk)*HDIM + d))*TSEQ + t + tx] = tile[tx][ty + i*8];
  }
}

// Flash attention v6: reads Q and K from the (const) fused qkv buffer,
// writes output to a SEPARATE compact buffer (round-7 aliasing structure:
// attention writes only a buffer nothing else touches concurrently).
// Diagonal-paired q-tiles, async inverse-swizzled staging, split-phase
// pipeline, fixed-offset softmax (|s|<=56.6 by RMS-norm bound).
__global__ __launch_bounds__(256, 2) void attn_kernel(
    const __hip_bfloat16* __restrict__ qkv, // [B][T][3072] (read-only here)
    const __hip_bfloat16* __restrict__ vt,  // [B][NKV][HD][T]
    __hip_bfloat16* __restrict__ out)       // [B][T][2048] attn output
{
  const int tid  = threadIdx.x;
  const int wave = tid >> 6;
  const int lane = tid & 63;
  const int qd = lane >> 4, ln = lane & 15;
  const int p  = blockIdx.x;     // pair index 0..15 -> q-tiles {p, 31-p}
  const int h  = blockIdx.y;
  const int b  = blockIdx.z;
  const int hk = h >> 2;

  const __hip_bfloat16* K = qkv + (size_t)(b*TSEQ)*QKVC + CDIM + hk*HDIM;
  const __hip_bfloat16* V = vt + ((size_t)(b*NKV + hk)*HDIM)*TSEQ;

  __shared__ __align__(16) __hip_bfloat16 Ks[64*128];    // [t][d], swizzled
  __shared__ __align__(16) __hip_bfloat16 Vs[128*64];    // [d][t], swizzled
  __shared__ __align__(16) __hip_bfloat16 Pb[4*16*64];   // per-wave P, swizzled

  auto issueK = [&](int t0) {
#pragma unroll
    for (int i = 0; i < 4; ++i) {
      int c = i*256 + tid;             // chunk; 16 chunks/row
      int row = c >> 4, cc = c & 15;
      int gcc = cc ^ (row & 15);
      async16(&K[(size_t)(t0 + row)*QKVC + gcc*8], &Ks[(i*256 + wave*64)*8]);
    }
  };
  auto issueV = [&](int t0) {
#pragma unroll
    for (int i = 0; i < 4; ++i) {
      int c = i*256 + tid;             // chunk; 8 chunks/row
      int row = c >> 3, cc = c & 7;
      int gcc = cc ^ (row & 7);
      async16(&V[(size_t)row*TSEQ + t0 + gcc*8], &Vs[(i*256 + wave*64)*8]);
    }
  };

#pragma unroll 1
  for (int seg = 0; seg < 2; ++seg) {
    const int qt = seg ? (31 - p) : p;
    const int q0 = qt * 64;
    const int qw = q0 + wave * 16;

    bf16x8 qfr[4];
#pragma unroll
    for (int kc = 0; kc < 4; ++kc)
      qfr[kc] = *(const bf16x8*)&qkv[((size_t)(b*TSEQ + qw + ln))*QKVC + h*HDIM + kc*32 + qd*8];

    f32x4 o[8] = {};
    float lacc[4] = {0.f, 0.f, 0.f, 0.f};

    __syncthreads();          // Ks free (prev segment's epilogue readback done)
    issueK(0);
    __syncthreads();          // drain K[0]

#pragma unroll 1
    for (int kt = 0; kt <= qt; ++kt) {
      const int t0 = kt * 64;
      issueV(t0);             // Vs free: PV[kt-1] done by all at loop-end sync

      f32x4 s[4] = {};
#pragma unroll
      for (int nt = 0; nt < 4; ++nt) {
#pragma unroll
        for (int kc = 0; kc < 4; ++kc) {
          bf16x8 kfr = *(const bf16x8*)&Ks[swz128(nt*16 + ln, kc*32 + qd*8)];
          s[nt] = mfma16(qfr[kc], kfr, s[nt]);
        }
      }
      if (kt == qt) {  // diagonal: causal mask
#pragma unroll
        for (int nt = 0; nt < 4; ++nt)
#pragma unroll
          for (int r = 0; r < 4; ++r) {
            int row = qw + qd*4 + r;
            int col = t0 + nt*16 + ln;
            if (col > row) s[nt][r] = -1.0e30f;
          }
      }
      // fixed-offset softmax: p = exp(s), defer l reduction
#pragma unroll
      for (int nt = 0; nt < 4; ++nt)
#pragma unroll
        for (int r = 0; r < 4; ++r)
          s[nt][r] = __expf(s[nt][r]);
#pragma unroll
      for (int r = 0; r < 4; ++r)
        lacc[r] += (s[0][r] + s[1][r]) + (s[2][r] + s[3][r]);

      __hip_bfloat16* Pw = &Pb[wave*1024];
#pragma unroll
      for (int nt = 0; nt < 4; ++nt)
#pragma unroll
        for (int r = 0; r < 4; ++r)
          Pw[swz64(qd*4 + r, nt*16 + ln)] = __float2bfloat16(s[nt][r]);
      bf16x8 pa[2];
#pragma unroll
      for (int kc = 0; kc < 2; ++kc)
        pa[kc] = *(const bf16x8*)&Pw[swz64(ln, kc*32 + qd*8)];

      __syncthreads();        // drain V[kt]; all waves done QK -> Ks free
      if (kt < qt) issueK(t0 + 64);   // overlaps PV

#pragma unroll
      for (int dt = 0; dt < 8; ++dt) {
#pragma unroll
        for (int kc = 0; kc < 2; ++kc) {
          bf16x8 vf = *(const bf16x8*)&Vs[swz64(dt*16 + ln, kc*32 + qd*8)];
          o[dt] = mfma16(pa[kc], vf, o[dt]);
        }
      }
      __syncthreads();        // drain K[kt+1]; all waves done PV -> Vs free
    }

    float inv[4];
#pragma unroll
    for (int r = 0; r < 4; ++r) {
      float lr = lacc[r];
      lr += __shfl_xor(lr, 1);
      lr += __shfl_xor(lr, 2);
      lr += __shfl_xor(lr, 4);
      lr += __shfl_xor(lr, 8);
      inv[r] = 1.0f / lr;
    }

    // coalesced epilogue via LDS (reuse Ks; wave-private 16x128 region)
    __hip_bfloat16* Ow = &Ks[wave*2048];
#pragma unroll
    for (int dt = 0; dt < 8; ++dt)
#pragma unroll
      for (int r = 0; r < 4; ++r)
        Ow[(qd*4 + r)*128 + dt*16 + ln] = __float2bfloat16(o[dt][r] * inv[r]);
    __syncthreads();          // writes visible before readback
#pragma unroll
    for (int pass = 0; pass < 4; ++pass) {
      int row = pass*4 + qd;
      bf16x8 val = *(const bf16x8*)&Ow[row*128 + ln*8];
      int q = qw + row;
      *(bf16x8*)&out[((size_t)(b*TSEQ + q))*CDIM + h*HDIM + ln*8] = val;
    }
  }
}

extern "C" void kernel_launch(void* const* d_in, const int* in_sizes, int n_in,
                              void* d_out, int out_size, void* d_ws, size_t ws_size,
                              hipStream_t stream) {
  char* ws = (char*)d_ws;
  size_t off = 0;
  auto alloc = [&](size_t bytes) { char* p = ws + off; off += (bytes + 255) & ~(size_t)255; return p; };

  int* flag = (int*)alloc(256);
  __hip_bfloat16* xb   = (__hip_bfloat16*)alloc((size_t)MROWS*CDIM*2);   // 16.8 MB (x, then attn out)
  __hip_bfloat16* wqkv = (__hip_bfloat16*)alloc((size_t)QKVC*CDIM*2);    // 12.6 MB
  __hip_bfloat16* wob  = (__hip_bfloat16*)alloc((size_t)CDIM*CDIM*2);    //  8.4 MB
  __hip_bfloat16* gb   = (__hip_bfloat16*)alloc(256);
  __hip_bfloat16* qkv  = (__hip_bfloat16*)alloc((size_t)MROWS*QKVC*2);   // 25.2 MB
  __hip_bfloat16* vt   = (__hip_bfloat16*)alloc((size_t)MROWS*KVC*2);    //  4.2 MB

  canary<<<1, 256, 0, stream>>>(d_in[0], flag);

  canonize_all<<<9217, 256, 0, stream>>>(
      d_in[0], d_in[1], d_in[2], d_in[3], d_in[4], d_in[5],
      xb, wqkv, wob, gb, flag);

  // fused QKV projection: [4096][2048] x [3072][2048]^T -> [4096][3072]
  gemm_bt<<<dim3(QKVC/128, MROWS/128), 256, 0, stream>>>(
      xb, wqkv, qkv, MROWS, QKVC, CDIM, CDIM);

  int nwaves = MROWS*NH + MROWS*NKV;
  prep_qk<<<nwaves/4, 256, 0, stream>>>(qkv, gb);

  transpose_v<<<dim3(MROWS/32, KVC/32), 256, 0, stream>>>(qkv, vt);

  // attention: reads qkv (const), writes attn output into xb (x is dead now)
  attn_kernel<<<dim3(TSEQ/128, NH, BATCH), 256, 0, stream>>>(qkv, vt, xb);

  // output projection reads compact attn output (lda = 2048)
  gemm_out<<<dim3(CDIM/128, MROWS/128), 256, 0, stream>>>(
      xb, wob, d_out, MROWS, CDIM, CDIM, CDIM, flag);
}